// Round 1
// 808.952 us; speedup vs baseline: 1.1993x; 1.1993x over previous
//
#include <hip/hip_runtime.h>
#include <hip/hip_bf16.h>
#include <hip/hip_fp16.h>
#include <stdint.h>

#define H 4
#define HID 64
#define CDIM 256   /* = H*HID = IN = FC */
#define OUTC 4
#define ALPHA 0.2f
#define NW 16      /* number of float weight inputs (d_in[2..17]) */

typedef __attribute__((ext_vector_type(8))) _Float16 f16x8;
typedef __attribute__((ext_vector_type(4))) float f32x4;

// ---------------------------------------------------------------------------
// dtype detection (R2/R4/R5-proven; real answer on this harness: fp32, flag=0)
// ---------------------------------------------------------------------------
__global__ void detect_k(const uint32_t* __restrict__ xw, int* __restrict__ flag) {
    __shared__ int sd[256];
    int t = threadIdx.x;
    int hits = 0;
    for (int i = 0; i < 16; ++i) {
        uint32_t w = xw[t * 16 + i];
        uint32_t ex = (w >> 7) & 0xffu;
        if (ex >= 100u && ex <= 145u) hits++;
    }
    sd[t] = hits;
    __syncthreads();
    for (int s = 128; s > 0; s >>= 1) {
        if (t < s) sd[t] += sd[t + s];
        __syncthreads();
    }
    if (t == 0) *flag = (sd[0] > 3000) ? 1 : 0;
}

// ---------------------------------------------------------------------------
// Convert all 16 weight tensors to fp32 AND fp16 in ws (branch on flag).
// ---------------------------------------------------------------------------
struct WPtrs {
    const void* p[NW];
    int sz[NW];
    int off[NW];
};

__global__ void convert_k(WPtrs ptrs, float* __restrict__ outf, __half* __restrict__ outh,
                          const int* __restrict__ flag) {
    int which = blockIdx.y;
    int n = ptrs.sz[which];
    int i = blockIdx.x * 256 + threadIdx.x;
    if (i >= n) return;
    float v;
    if (*flag) v = __bfloat162float(((const __hip_bfloat16*)ptrs.p[which])[i]);
    else       v = ((const float*)ptrs.p[which])[i];
    outf[ptrs.off[which] + i] = v;
    outh[ptrs.off[which] + i] = __float2half(v);
}

// ---------------------------------------------------------------------------
// CSR build: histogram -> scan -> scatter (stores dst and src per slot)
// ---------------------------------------------------------------------------
__global__ void hist_k(const int* __restrict__ srcI, int* __restrict__ counts, int Ee) {
    int e = blockIdx.x * 256 + threadIdx.x;
    if (e < Ee) atomicAdd(&counts[srcI[e]], 1);
}

__global__ void scan1_k(const int* __restrict__ counts, int* __restrict__ bs, int Nn) {
    __shared__ int sd[256];
    int t = threadIdx.x;
    int i = blockIdx.x * 256 + t;
    sd[t] = (i < Nn) ? counts[i] : 0;
    __syncthreads();
    for (int s = 128; s > 0; s >>= 1) {
        if (t < s) sd[t] += sd[t + s];
        __syncthreads();
    }
    if (t == 0) bs[blockIdx.x] = sd[0];
}

__global__ void scan2_k(int* __restrict__ bs, int nb) {
    __shared__ int sd[512];
    int t = threadIdx.x;
    int v = (t < nb) ? bs[t] : 0;
    sd[t] = v;
    __syncthreads();
    for (int offm = 1; offm < 512; offm <<= 1) {
        int add = (t >= offm) ? sd[t - offm] : 0;
        __syncthreads();
        sd[t] += add;
        __syncthreads();
    }
    if (t < nb) bs[t] = sd[t] - v;   // exclusive
}

__global__ void scan3_k(const int* __restrict__ counts, const int* __restrict__ bs,
                        int* __restrict__ rowStart, int* __restrict__ cur, int Nn, int Ee) {
    __shared__ int sd[256];
    int t = threadIdx.x;
    int i = blockIdx.x * 256 + t;
    int v = (i < Nn) ? counts[i] : 0;
    sd[t] = v;
    __syncthreads();
    for (int offm = 1; offm < 256; offm <<= 1) {
        int add = (t >= offm) ? sd[t - offm] : 0;
        __syncthreads();
        sd[t] += add;
        __syncthreads();
    }
    int excl = sd[t] - v + bs[blockIdx.x];
    if (i < Nn) { rowStart[i] = excl; cur[i] = excl; }
    if (i == Nn) rowStart[i] = Ee;
}

__global__ void scatter_k(const int* __restrict__ srcI, const int* __restrict__ dstI,
                          int* __restrict__ cur, int* __restrict__ colI,
                          int* __restrict__ colSrc, int Ee) {
    int e = blockIdx.x * 256 + threadIdx.x;
    if (e < Ee) {
        int s = srcI[e];
        int p = atomicAdd(&cur[s], 1);
        colI[p] = dstI[e];
        colSrc[p] = s;
    }
}

// ---------------------------------------------------------------------------
// f16 MFMA GEMM, 128x128 tile / 4 waves, BK=32, mfma_f32_16x16x32_f16.
// AMODE 0: A = raw x (fp32 or bf16 per *flag), convert to fp16 in staging.
// AMODE 1: A = fp16 n-major [M][256].
// OMODE 0: fp32 n-major out + bias + relu (collator).
// OMODE 1: fp16 n-major out [M][256] (pre-relu, no bias) + fused attention
//          scores a1v/a2v[n][head] (head's 64 dims sit inside this block's
//          128 cols -> no atomics, exact ownership).
// ---------------------------------------------------------------------------
template <int AMODE, int OMODE>
__global__ __launch_bounds__(256) void gemm_k(
    const void* __restrict__ Ap, const __half* __restrict__ B,
    const float* __restrict__ bias, void* __restrict__ Cp, int M,
    const int* __restrict__ flagp,
    const float* __restrict__ a1w, const float* __restrict__ a1b,
    const float* __restrict__ a2w, const float* __restrict__ a2b,
    float* __restrict__ a1v, float* __restrict__ a2v)
{
    __shared__ __align__(16) char smem[128 * 136 * 2];   // 34.8 KB
    short* As = (short*)smem;              // 128*40 shorts
    short* Bs = (short*)(smem + 10240);
    const int tid  = threadIdx.x;
    const int row0 = blockIdx.x * 128;
    const int col0 = blockIdx.y * 128;
    const int wave = tid >> 6, lane = tid & 63;
    const int m0w = (wave & 1) * 64;
    const int n0w = (wave >> 1) * 64;
    const int lm = lane & 15, lg = lane >> 4;
    const int isbf = (AMODE == 0) ? *flagp : 0;

    f32x4 acc[4][4] = {};

    for (int k0 = 0; k0 < CDIM; k0 += 32) {
        #pragma unroll
        for (int l = 0; l < 2; ++l) {
            int c = tid + l * 256;
            int m = c >> 2, kc = c & 3;
            int gr = row0 + m;
            uint4 q = make_uint4(0u, 0u, 0u, 0u);
            if constexpr (AMODE == 1) {
                const __half* A = (const __half*)Ap;
                if (gr < M) q = *(const uint4*)(A + (size_t)gr * CDIM + k0 + kc * 8);
            } else {
                if (gr < M) {
                    __half hv[8];
                    if (isbf) {
                        const uint4 qb = *(const uint4*)((const __hip_bfloat16*)Ap
                                           + (size_t)gr * CDIM + k0 + kc * 8);
                        const uint32_t* w = (const uint32_t*)&qb;
                        #pragma unroll
                        for (int p = 0; p < 4; ++p) {
                            hv[2*p]   = __float2half(__uint_as_float((w[p] & 0xffffu) << 16));
                            hv[2*p+1] = __float2half(__uint_as_float(w[p] & 0xffff0000u));
                        }
                    } else {
                        const float* A = (const float*)Ap + (size_t)gr * CDIM + k0 + kc * 8;
                        const float4 f0 = *(const float4*)A;
                        const float4 f1 = *(const float4*)(A + 4);
                        hv[0]=__float2half(f0.x); hv[1]=__float2half(f0.y);
                        hv[2]=__float2half(f0.z); hv[3]=__float2half(f0.w);
                        hv[4]=__float2half(f1.x); hv[5]=__float2half(f1.y);
                        hv[6]=__float2half(f1.z); hv[7]=__float2half(f1.w);
                    }
                    q = *(uint4*)hv;
                }
            }
            *(uint4*)(&As[m * 40 + kc * 8]) = q;
        }
        #pragma unroll
        for (int l = 0; l < 2; ++l) {
            int c = tid + l * 256;
            int nn = c >> 2, kc = c & 3;
            uint4 q = *(const uint4*)(B + (size_t)(col0 + nn) * CDIM + k0 + kc * 8);
            *(uint4*)(&Bs[nn * 40 + kc * 8]) = q;
        }
        __syncthreads();
        f16x8 af[4], bfr[4];
        #pragma unroll
        for (int i = 0; i < 4; ++i)
            af[i] = *(f16x8*)(&As[(m0w + i * 16 + lm) * 40 + lg * 8]);
        #pragma unroll
        for (int j = 0; j < 4; ++j)
            bfr[j] = *(f16x8*)(&Bs[(n0w + j * 16 + lm) * 40 + lg * 8]);
        #pragma unroll
        for (int i = 0; i < 4; ++i)
            #pragma unroll
            for (int j = 0; j < 4; ++j)
                acc[i][j] = __builtin_amdgcn_mfma_f32_16x16x32_f16(
                    af[i], bfr[j], acc[i][j], 0, 0, 0);
        __syncthreads();
    }

    if constexpr (OMODE == 1) {
        // fp16 tile -> LDS; n-major coalesced stores + fused scores
        __half (*Cs)[136] = (__half(*)[136])smem;
        #pragma unroll
        for (int i = 0; i < 4; ++i)
            #pragma unroll
            for (int r = 0; r < 4; ++r) {
                int lr = m0w + i * 16 + lg * 4 + r;
                #pragma unroll
                for (int j = 0; j < 4; ++j)
                    Cs[lr][n0w + j * 16 + lm] = __float2half(acc[i][j][r]);
            }
        __syncthreads();
        __half* C = (__half*)Cp;
        #pragma unroll
        for (int l = 0; l < 8; ++l) {
            int c = tid + l * 256;
            int rr = c >> 4, cc = c & 15;
            int gr = row0 + rr;
            if (gr < M)
                *(uint4*)(C + (size_t)gr * CDIM + col0 + cc * 8) = *(uint4*)(&Cs[rr][cc * 8]);
        }
        // fused scores: thread t -> (row t>>1, head-sel t&1); block covers 2 heads
        {
            int row = tid >> 1, hsel = tid & 1;
            int gr = row0 + row;
            if (gr < M) {
                int ghead = (col0 >> 6) + hsel;
                const float* w1 = a1w + ghead * 64;
                const float* w2 = a2w + ghead * 64;
                const uint* cp = (const uint*)&Cs[row][hsel * 64];
                float s1 = 0.f, s2 = 0.f;
                #pragma unroll
                for (int j = 0; j < 32; ++j) {
                    uint u = cp[j];
                    float2 f = __half22float2(*(__half2*)&u);
                    s1 += f.x * w1[2*j] + f.y * w1[2*j+1];
                    s2 += f.x * w2[2*j] + f.y * w2[2*j+1];
                }
                a1v[(size_t)gr * H + ghead] = s1 + a1b[ghead];
                a2v[(size_t)gr * H + ghead] = s2 + a2b[ghead];
            }
        }
    } else {
        float* C = (float*)Cp;
        #pragma unroll
        for (int i = 0; i < 4; ++i)
            #pragma unroll
            for (int r = 0; r < 4; ++r) {
                int grow = row0 + m0w + i * 16 + lg * 4 + r;
                if (grow < M) {
                    #pragma unroll
                    for (int j = 0; j < 4; ++j) {
                        int gcol = col0 + n0w + j * 16 + lm;
                        float t = fmaxf(acc[i][j][r] + bias[gcol], 0.f);
                        C[(size_t)grow * CDIM + gcol] = t;
                    }
                }
            }
    }
}

// ---------------------------------------------------------------------------
// Edge scores: thread t -> (slot p = t>>2, head = t&3).
// Removes the colI->a2->exp dependent chain (and 16x-redundant exp) from agg.
// ---------------------------------------------------------------------------
__global__ void escore_k(const int* __restrict__ colSrc, const int* __restrict__ colI,
                         const float* __restrict__ a1, const float* __restrict__ a2,
                         float* __restrict__ sExp, int Ee)
{
    int t = blockIdx.x * 256 + threadIdx.x;
    if (t >= Ee * 4) return;
    int p = t >> 2, head = t & 3;
    float z = a1[(size_t)colSrc[p] * H + head] + a2[(size_t)colI[p] * H + head];
    z = (z > 0.f) ? z : ALPHA * z;
    sExp[t] = __expf(z);
}

// ---------------------------------------------------------------------------
// Edge aggregation (R6 restructure: latency -> MLP).
// OLD: 4 waves per node, 1 row-gather in flight per wave (depth-1 prefetch),
//      LDS cross-wave reduce. Latency-bound: 195us vs 73us HBM floor.
// NEW: 1 wave per node (4 nodes/block). Lane owns dims lane*4..lane*4+3
//      (ushort4 = 8B/lane -> full 512B row per wave-instr, unchanged
//      coalescing). Edge loop unrolled 8-deep: batch 8 colI/sExp loads
//      (wave-uniform -> scalar), then 8 independent row gathers in flight,
//      then accumulate. MLP/wave 1 -> 8. Denominator is wave-complete ->
//      no LDS, no __syncthreads, direct ushort4 store.
//      Guards (p<e) are wave-uniform -> scalar branches, no divergence,
//      no wasted tail gathers. Registers ~48-56 VGPR -> still 8 waves/SIMD.
// ---------------------------------------------------------------------------
__global__ __launch_bounds__(256) void agg_k(
    const __half* __restrict__ h, const float* __restrict__ sExp,
    const int* __restrict__ rowStart, const int* __restrict__ colI,
    const float* __restrict__ bias, __half* __restrict__ outp, int relu, int Nn)
{
    int tid = threadIdx.x;
    int wave = tid >> 6, lane = tid & 63;
    int n = blockIdx.x * 4 + wave;
    if (n >= Nn) return;
    int head = lane >> 4;
    int s = rowStart[n], e = rowStart[n + 1];
    float ac0 = 0.f, ac1 = 0.f, ac2 = 0.f, ac3 = 0.f, den = 0.f;
    const __half* hl = h + lane * 4;

    for (int p0 = s; p0 < e; p0 += 8) {
        int d[8]; float sv[8]; ushort4 u[8];
        #pragma unroll
        for (int q = 0; q < 8; ++q) {
            int p = p0 + q;
            if (p < e) {
                d[q]  = colI[p];
                sv[q] = sExp[(size_t)p * H + head];
            }
        }
        #pragma unroll
        for (int q = 0; q < 8; ++q) {
            if (p0 + q < e)
                u[q] = *(const ushort4*)(hl + (size_t)d[q] * CDIM);
        }
        #pragma unroll
        for (int q = 0; q < 8; ++q) {
            if (p0 + q < e) {
                float svq = sv[q];
                den += svq;
                ac0 = fmaf(svq, __half2float(__ushort_as_half(u[q].x)), ac0);
                ac1 = fmaf(svq, __half2float(__ushort_as_half(u[q].y)), ac1);
                ac2 = fmaf(svq, __half2float(__ushort_as_half(u[q].z)), ac2);
                ac3 = fmaf(svq, __half2float(__ushort_as_half(u[q].w)), ac3);
            }
        }
    }

    den = (den > 0.f) ? den : 1.f;
    const float4 b4 = *(const float4*)(bias + lane * 4);
    float r0 = ac0 / den + b4.x;
    float r1 = ac1 / den + b4.y;
    float r2 = ac2 / den + b4.z;
    float r3 = ac3 / den + b4.w;
    if (relu) {
        r0 = fmaxf(r0, 0.f); r1 = fmaxf(r1, 0.f);
        r2 = fmaxf(r2, 0.f); r3 = fmaxf(r3, 0.f);
    }
    ushort4 o;
    o.x = __half_as_ushort(__float2half(r0));
    o.y = __half_as_ushort(__float2half(r1));
    o.z = __half_as_ushort(__float2half(r2));
    o.w = __half_as_ushort(__float2half(r3));
    *(ushort4*)(outp + (size_t)n * CDIM + lane * 4) = o;
}

// ---------------------------------------------------------------------------
// Classifier: one wave per node; output dtype per flag (proven).
// ---------------------------------------------------------------------------
__global__ __launch_bounds__(256) void cls_k(
    const float* __restrict__ feat, const float* __restrict__ Wcls,
    const float* __restrict__ bcls, void* __restrict__ out, int Nn,
    const int* __restrict__ flagp)
{
    int gtid = blockIdx.x * 256 + threadIdx.x;
    int n = gtid >> 6;
    int lane = threadIdx.x & 63;
    if (n >= Nn) return;
    const float* f = feat + (size_t)n * CDIM;
    float p0 = 0.f, p1 = 0.f, p2 = 0.f, p3 = 0.f;
    for (int k = lane; k < CDIM; k += 64) {
        float fv = f[k];
        p0 = fmaf(fv, Wcls[0 * CDIM + k], p0);
        p1 = fmaf(fv, Wcls[1 * CDIM + k], p1);
        p2 = fmaf(fv, Wcls[2 * CDIM + k], p2);
        p3 = fmaf(fv, Wcls[3 * CDIM + k], p3);
    }
    #pragma unroll
    for (int off = 32; off > 0; off >>= 1) {
        p0 += __shfl_xor(p0, off);
        p1 += __shfl_xor(p1, off);
        p2 += __shfl_xor(p2, off);
        p3 += __shfl_xor(p3, off);
    }
    if (lane < OUTC) {
        float pv = (lane == 0) ? p0 : (lane == 1) ? p1 : (lane == 2) ? p2 : p3;
        pv += bcls[lane];
        if (*flagp) ((__hip_bfloat16*)out)[(size_t)n * OUTC + lane] = __float2bfloat16(pv);
        else        ((float*)out)[(size_t)n * OUTC + lane] = pv;
    }
}

// ---------------------------------------------------------------------------
extern "C" void kernel_launch(void* const* d_in, const int* in_sizes, int n_in,
                              void* d_out, int out_size, void* d_ws, size_t ws_size,
                              hipStream_t stream)
{
    const void* x  = d_in[0];
    const int*  ei = (const int*)d_in[1];

    const int Nn = in_sizes[0] / CDIM;   // 100000
    const int Ee = in_sizes[1] / 2;      // 1600000
    const int* srcI = ei;
    const int* dstI = ei + Ee;

    char* wsp = (char*)d_ws;
    size_t off = 0;
    auto alloc = [&](size_t bytes) -> void* {
        void* p = wsp + off;
        off += (bytes + 255) & ~(size_t)255;
        return p;
    };
    __half* hA   = (__half*)alloc((size_t)Nn * CDIM * 2);  // 51.2 MB
    __half* hB   = (__half*)alloc((size_t)Nn * CDIM * 2);  // 51.2 MB
    float*  bufA = (float*)alloc((size_t)Nn * CDIM * 4);   // 102.4 MB fp32 collator out
    float*  a1v       = (float*)alloc((size_t)Nn * H * 4);
    float*  a2v       = (float*)alloc((size_t)Nn * H * 4);
    float*  sExp      = (float*)alloc((size_t)Ee * H * 4); // 25.6 MB
    int*    rowStart  = (int*)alloc((size_t)(Nn + 1) * 4);
    int*    cursor    = (int*)alloc((size_t)Nn * 4);
    int*    colI      = (int*)alloc((size_t)Ee * 4);       // 6.4 MB
    int*    colSrc    = (int*)alloc((size_t)Ee * 4);       // 6.4 MB
    int*    blockSums = (int*)alloc(512 * 4);
    int*    flag      = (int*)alloc(256);
    float*  wconv     = (float*)alloc((size_t)200000 * 4);
    __half* wh        = (__half*)alloc((size_t)200000 * 2);
    (void)ws_size; (void)n_in; (void)out_size;

    // dtype detect + weight conversion (proven machinery)
    detect_k<<<1, 256, 0, stream>>>((const uint32_t*)x, flag);
    WPtrs wp;
    int woff = 0;
    for (int i = 0; i < NW; ++i) {
        wp.p[i] = d_in[2 + i];
        wp.sz[i] = in_sizes[2 + i];
        wp.off[i] = woff;
        woff += in_sizes[2 + i];
    }
    {
        dim3 cgrid(256, NW);
        convert_k<<<cgrid, 256, 0, stream>>>(wp, wconv, wh, flag);
    }
    const float*  a11wf = wconv + wp.off[1];
    const float*  a11bf = wconv + wp.off[2];
    const float*  a12wf = wconv + wp.off[3];
    const float*  a12bf = wconv + wp.off[4];
    const float*  b1f   = wconv + wp.off[5];
    const float*  a21wf = wconv + wp.off[7];
    const float*  a21bf = wconv + wp.off[8];
    const float*  a22wf = wconv + wp.off[9];
    const float*  a22bf = wconv + wp.off[10];
    const float*  b2f   = wconv + wp.off[11];
    const float*  bcf   = wconv + wp.off[13];
    const float*  Wclsf = wconv + wp.off[14];
    const float*  bclsf = wconv + wp.off[15];
    const __half* W1h   = wh + wp.off[0];
    const __half* W2h   = wh + wp.off[6];
    const __half* Wch   = wh + wp.off[12];

    const int NB = (Nn + 255) / 256;   // 391 (fits scan2's 512)
    const int EB = (Ee + 255) / 256;
    const int SB = (Ee * 4 + 255) / 256;

    // CSR build
    hipMemsetAsync(cursor, 0, (size_t)Nn * 4, stream);
    hist_k<<<EB, 256, 0, stream>>>(srcI, cursor, Ee);
    scan1_k<<<NB, 256, 0, stream>>>(cursor, blockSums, Nn);
    scan2_k<<<1, 512, 0, stream>>>(blockSums, NB);
    scan3_k<<<NB, 256, 0, stream>>>(cursor, blockSums, rowStart, cursor, Nn, Ee);
    scatter_k<<<EB, 256, 0, stream>>>(srcI, dstI, cursor, colI, colSrc, Ee);

    dim3 ggrid((Nn + 127) / 128, CDIM / 128);   // (782, 2)
    const int AB = (Nn + 3) / 4;                // 4 nodes (waves) per block

    // Layer 1: gemm(raw x) -> hA (+ fused scores); escore; agg -> hB (relu)
    gemm_k<0, 1><<<ggrid, 256, 0, stream>>>(x, W1h, nullptr, hA, Nn, flag,
                                            a11wf, a11bf, a12wf, a12bf, a1v, a2v);
    escore_k<<<SB, 256, 0, stream>>>(colSrc, colI, a1v, a2v, sExp, Ee);
    agg_k<<<AB, 256, 0, stream>>>(hA, sExp, rowStart, colI, b1f, hB, 1, Nn);

    // Layer 2: gemm(hB) -> hA (+ fused scores); escore; agg -> hB
    gemm_k<1, 1><<<ggrid, 256, 0, stream>>>(hB, W2h, nullptr, hA, Nn, flag,
                                            a21wf, a21bf, a22wf, a22bf, a1v, a2v);
    escore_k<<<SB, 256, 0, stream>>>(colSrc, colI, a1v, a2v, sExp, Ee);
    agg_k<<<AB, 256, 0, stream>>>(hA, sExp, rowStart, colI, b2f, hB, 0, Nn);

    // Collator (fp32 + bias + relu) + classifier
    gemm_k<1, 0><<<ggrid, 256, 0, stream>>>(hB, Wch, bcf, bufA, Nn, flag,
                                            nullptr, nullptr, nullptr, nullptr,
                                            nullptr, nullptr);
    cls_k<<<(Nn * 64 + 255) / 256, 256, 0, stream>>>(bufA, Wclsf, bclsf,
                                                     d_out, Nn, flag);
}

// Round 3
// 802.897 us; speedup vs baseline: 1.2083x; 1.0075x over previous
//
#include <hip/hip_runtime.h>
#include <hip/hip_bf16.h>
#include <hip/hip_fp16.h>
#include <stdint.h>

#define H 4
#define HID 64
#define CDIM 256   /* = H*HID = IN = FC */
#define OUTC 4
#define ALPHA 0.2f
#define NW 16      /* number of float weight inputs (d_in[2..17]) */

typedef __attribute__((ext_vector_type(8))) _Float16 f16x8;
typedef __attribute__((ext_vector_type(4))) float f32x4;

// ---------------------------------------------------------------------------
// dtype detection (R2/R4/R5-proven; real answer on this harness: fp32, flag=0)
// ---------------------------------------------------------------------------
__global__ void detect_k(const uint32_t* __restrict__ xw, int* __restrict__ flag) {
    __shared__ int sd[256];
    int t = threadIdx.x;
    int hits = 0;
    for (int i = 0; i < 16; ++i) {
        uint32_t w = xw[t * 16 + i];
        uint32_t ex = (w >> 7) & 0xffu;
        if (ex >= 100u && ex <= 145u) hits++;
    }
    sd[t] = hits;
    __syncthreads();
    for (int s = 128; s > 0; s >>= 1) {
        if (t < s) sd[t] += sd[t + s];
        __syncthreads();
    }
    if (t == 0) *flag = (sd[0] > 3000) ? 1 : 0;
}

// ---------------------------------------------------------------------------
// Convert all 16 weight tensors to fp32 AND fp16 in ws (branch on flag).
// ---------------------------------------------------------------------------
struct WPtrs {
    const void* p[NW];
    int sz[NW];
    int off[NW];
};

__global__ void convert_k(WPtrs ptrs, float* __restrict__ outf, __half* __restrict__ outh,
                          const int* __restrict__ flag) {
    int which = blockIdx.y;
    int n = ptrs.sz[which];
    int i = blockIdx.x * 256 + threadIdx.x;
    if (i >= n) return;
    float v;
    if (*flag) v = __bfloat162float(((const __hip_bfloat16*)ptrs.p[which])[i]);
    else       v = ((const float*)ptrs.p[which])[i];
    outf[ptrs.off[which] + i] = v;
    outh[ptrs.off[which] + i] = __float2half(v);
}

// ---------------------------------------------------------------------------
// CSR build: histogram -> scan -> scatter (R7: colI only; src implicit in row)
// ---------------------------------------------------------------------------
__global__ void hist_k(const int* __restrict__ srcI, int* __restrict__ counts, int Ee) {
    int e = blockIdx.x * 256 + threadIdx.x;
    if (e < Ee) atomicAdd(&counts[srcI[e]], 1);
}

__global__ void scan1_k(const int* __restrict__ counts, int* __restrict__ bs, int Nn) {
    __shared__ int sd[256];
    int t = threadIdx.x;
    int i = blockIdx.x * 256 + t;
    sd[t] = (i < Nn) ? counts[i] : 0;
    __syncthreads();
    for (int s = 128; s > 0; s >>= 1) {
        if (t < s) sd[t] += sd[t + s];
        __syncthreads();
    }
    if (t == 0) bs[blockIdx.x] = sd[0];
}

__global__ void scan2_k(int* __restrict__ bs, int nb) {
    __shared__ int sd[512];
    int t = threadIdx.x;
    int v = (t < nb) ? bs[t] : 0;
    sd[t] = v;
    __syncthreads();
    for (int offm = 1; offm < 512; offm <<= 1) {
        int add = (t >= offm) ? sd[t - offm] : 0;
        __syncthreads();
        sd[t] += add;
        __syncthreads();
    }
    if (t < nb) bs[t] = sd[t] - v;   // exclusive
}

__global__ void scan3_k(const int* __restrict__ counts, const int* __restrict__ bs,
                        int* __restrict__ rowStart, int* __restrict__ cur, int Nn, int Ee) {
    __shared__ int sd[256];
    int t = threadIdx.x;
    int i = blockIdx.x * 256 + t;
    int v = (i < Nn) ? counts[i] : 0;
    sd[t] = v;
    __syncthreads();
    for (int offm = 1; offm < 256; offm <<= 1) {
        int add = (t >= offm) ? sd[t - offm] : 0;
        __syncthreads();
        sd[t] += add;
        __syncthreads();
    }
    int excl = sd[t] - v + bs[blockIdx.x];
    if (i < Nn) { rowStart[i] = excl; cur[i] = excl; }
    if (i == Nn) rowStart[i] = Ee;
}

// R7: single random 4B write per edge (was 2 -> write-allocate traffic halves)
__global__ void scatter_k(const int* __restrict__ srcI, const int* __restrict__ dstI,
                          int* __restrict__ cur, int* __restrict__ colI, int Ee) {
    int e = blockIdx.x * 256 + threadIdx.x;
    if (e < Ee) {
        int s = srcI[e];
        int p = atomicAdd(&cur[s], 1);
        colI[p] = dstI[e];
    }
}

// ---------------------------------------------------------------------------
// f16 MFMA GEMM, 128x128 tile / 4 waves, BK=32, mfma_f32_16x16x32_f16.
// AMODE 0: A = raw x (fp32 or bf16 per *flag), convert to fp16 in staging.
// AMODE 1: A = fp16 n-major [M][256].
// OMODE 0: collator + FUSED classifier (R8 fix): relu(acc+bias) never leaves
//          registers; per-row partial logits over this wave's 64 cols are
//          shuffle-reduced and written to pcls[row][blockIdx.y*2 + (wave>>1)]
//          -- each wave owns a DISTINCT slot (R2 bug: two waves with the same
//          rows but different n0w clobbered one shared slot). cls2_k sums 4.
// OMODE 1: fp16 n-major out [M][256] (pre-relu, no bias) + fused attention
//          scores a1v/a2v[n][head] (head's 64 dims sit inside this block's
//          128 cols -> no atomics, exact ownership).
// ---------------------------------------------------------------------------
template <int AMODE, int OMODE>
__global__ __launch_bounds__(256) void gemm_k(
    const void* __restrict__ Ap, const __half* __restrict__ B,
    const float* __restrict__ bias, void* __restrict__ Cp, int M,
    const int* __restrict__ flagp,
    const float* __restrict__ a1w, const float* __restrict__ a1b,
    const float* __restrict__ a2w, const float* __restrict__ a2b,
    float* __restrict__ a1v, float* __restrict__ a2v)
{
    __shared__ __align__(16) char smem[128 * 136 * 2];   // 34.8 KB
    short* As = (short*)smem;              // 128*40 shorts
    short* Bs = (short*)(smem + 10240);
    const int tid  = threadIdx.x;
    const int row0 = blockIdx.x * 128;
    const int col0 = blockIdx.y * 128;
    const int wave = tid >> 6, lane = tid & 63;
    const int m0w = (wave & 1) * 64;
    const int n0w = (wave >> 1) * 64;
    const int lm = lane & 15, lg = lane >> 4;
    const int isbf = (AMODE == 0) ? *flagp : 0;

    f32x4 acc[4][4] = {};

    for (int k0 = 0; k0 < CDIM; k0 += 32) {
        #pragma unroll
        for (int l = 0; l < 2; ++l) {
            int c = tid + l * 256;
            int m = c >> 2, kc = c & 3;
            int gr = row0 + m;
            uint4 q = make_uint4(0u, 0u, 0u, 0u);
            if constexpr (AMODE == 1) {
                const __half* A = (const __half*)Ap;
                if (gr < M) q = *(const uint4*)(A + (size_t)gr * CDIM + k0 + kc * 8);
            } else {
                if (gr < M) {
                    __half hv[8];
                    if (isbf) {
                        const uint4 qb = *(const uint4*)((const __hip_bfloat16*)Ap
                                           + (size_t)gr * CDIM + k0 + kc * 8);
                        const uint32_t* w = (const uint32_t*)&qb;
                        #pragma unroll
                        for (int p = 0; p < 4; ++p) {
                            hv[2*p]   = __float2half(__uint_as_float((w[p] & 0xffffu) << 16));
                            hv[2*p+1] = __float2half(__uint_as_float(w[p] & 0xffff0000u));
                        }
                    } else {
                        const float* A = (const float*)Ap + (size_t)gr * CDIM + k0 + kc * 8;
                        const float4 f0 = *(const float4*)A;
                        const float4 f1 = *(const float4*)(A + 4);
                        hv[0]=__float2half(f0.x); hv[1]=__float2half(f0.y);
                        hv[2]=__float2half(f0.z); hv[3]=__float2half(f0.w);
                        hv[4]=__float2half(f1.x); hv[5]=__float2half(f1.y);
                        hv[6]=__float2half(f1.z); hv[7]=__float2half(f1.w);
                    }
                    q = *(uint4*)hv;
                }
            }
            *(uint4*)(&As[m * 40 + kc * 8]) = q;
        }
        #pragma unroll
        for (int l = 0; l < 2; ++l) {
            int c = tid + l * 256;
            int nn = c >> 2, kc = c & 3;
            uint4 q = *(const uint4*)(B + (size_t)(col0 + nn) * CDIM + k0 + kc * 8);
            *(uint4*)(&Bs[nn * 40 + kc * 8]) = q;
        }
        __syncthreads();
        f16x8 af[4], bfr[4];
        #pragma unroll
        for (int i = 0; i < 4; ++i)
            af[i] = *(f16x8*)(&As[(m0w + i * 16 + lm) * 40 + lg * 8]);
        #pragma unroll
        for (int j = 0; j < 4; ++j)
            bfr[j] = *(f16x8*)(&Bs[(n0w + j * 16 + lm) * 40 + lg * 8]);
        #pragma unroll
        for (int i = 0; i < 4; ++i)
            #pragma unroll
            for (int j = 0; j < 4; ++j)
                acc[i][j] = __builtin_amdgcn_mfma_f32_16x16x32_f16(
                    af[i], bfr[j], acc[i][j], 0, 0, 0);
        __syncthreads();
    }

    if constexpr (OMODE == 1) {
        // fp16 tile -> LDS; n-major coalesced stores + fused scores
        __half (*Cs)[136] = (__half(*)[136])smem;
        #pragma unroll
        for (int i = 0; i < 4; ++i)
            #pragma unroll
            for (int r = 0; r < 4; ++r) {
                int lr = m0w + i * 16 + lg * 4 + r;
                #pragma unroll
                for (int j = 0; j < 4; ++j)
                    Cs[lr][n0w + j * 16 + lm] = __float2half(acc[i][j][r]);
            }
        __syncthreads();
        __half* C = (__half*)Cp;
        #pragma unroll
        for (int l = 0; l < 8; ++l) {
            int c = tid + l * 256;
            int rr = c >> 4, cc = c & 15;
            int gr = row0 + rr;
            if (gr < M)
                *(uint4*)(C + (size_t)gr * CDIM + col0 + cc * 8) = *(uint4*)(&Cs[rr][cc * 8]);
        }
        // fused scores: thread t -> (row t>>1, head-sel t&1); block covers 2 heads
        {
            int row = tid >> 1, hsel = tid & 1;
            int gr = row0 + row;
            if (gr < M) {
                int ghead = (col0 >> 6) + hsel;
                const float* w1 = a1w + ghead * 64;
                const float* w2 = a2w + ghead * 64;
                const uint* cp = (const uint*)&Cs[row][hsel * 64];
                float s1 = 0.f, s2 = 0.f;
                #pragma unroll
                for (int j = 0; j < 32; ++j) {
                    uint u = cp[j];
                    float2 f = __half22float2(*(__half2*)&u);
                    s1 += f.x * w1[2*j] + f.y * w1[2*j+1];
                    s2 += f.x * w2[2*j] + f.y * w2[2*j+1];
                }
                a1v[(size_t)gr * H + ghead] = s1 + a1b[ghead];
                a2v[(size_t)gr * H + ghead] = s2 + a2b[ghead];
            }
        }
    } else {
        // collator + fused classifier partials (R8). feat stays in registers.
        // Each wave reduces its own 64 cols; slot = blockIdx.y*2 + (wave>>1)
        // (4 distinct slots per row across the 2 y-blocks x 2 n-waves).
        const float* Wc4 = a1w;     // Wcls [OUTC][CDIM] fp32
        float* pcls = a1v;          // [M][4][OUTC] partials
        const int slot = blockIdx.y * 2 + (wave >> 1);
        float wv[OUTC][4];
        #pragma unroll
        for (int o = 0; o < OUTC; ++o)
            #pragma unroll
            for (int j = 0; j < 4; ++j)
                wv[o][j] = Wc4[o * CDIM + col0 + n0w + j * 16 + lm];
        #pragma unroll
        for (int i = 0; i < 4; ++i)
            #pragma unroll
            for (int r = 0; r < 4; ++r) {
                int grow = row0 + m0w + i * 16 + lg * 4 + r;
                if (grow < M) {
                    float po[OUTC] = {0.f, 0.f, 0.f, 0.f};
                    #pragma unroll
                    for (int j = 0; j < 4; ++j) {
                        int gcol = col0 + n0w + j * 16 + lm;
                        float t = fmaxf(acc[i][j][r] + bias[gcol], 0.f);
                        #pragma unroll
                        for (int o = 0; o < OUTC; ++o)
                            po[o] = fmaf(t, wv[o][j], po[o]);
                    }
                    // reduce over the 16 lanes (lm) sharing this row
                    #pragma unroll
                    for (int m = 1; m < 16; m <<= 1)
                        #pragma unroll
                        for (int o = 0; o < OUTC; ++o)
                            po[o] += __shfl_xor(po[o], m);
                    if (lm < OUTC) {
                        float v = (lm == 0) ? po[0] : (lm == 1) ? po[1]
                                : (lm == 2) ? po[2] : po[3];
                        pcls[((size_t)grow * 4 + slot) * OUTC + lm] = v;
                    }
                }
            }
        (void)Cp;
    }
}

// ---------------------------------------------------------------------------
// Edge scores, per-node (R7): one wave per node; src = n implicitly (colSrc
// eliminated). Item idx -> (slot = s + idx>>2, head = idx&3); head is
// loop-invariant per lane -> a1[n][head] loaded once. a2 table (1.6 MB) is
// L2-resident. sExp writes are contiguous [s*4, e*4).
// ---------------------------------------------------------------------------
__global__ __launch_bounds__(256) void escore_k(
    const int* __restrict__ rowStart, const int* __restrict__ colI,
    const float* __restrict__ a1, const float* __restrict__ a2,
    float* __restrict__ sExp, int Nn)
{
    int tid = threadIdx.x;
    int wave = tid >> 6, lane = tid & 63;
    int n = blockIdx.x * 4 + wave;
    if (n >= Nn) return;
    int head = lane & 3;
    int s = rowStart[n], e = rowStart[n + 1];
    float a1n = a1[(size_t)n * H + head];
    for (int idx = lane; ; idx += 64) {
        int slot = s + (idx >> 2);
        if (slot >= e) break;
        int d = colI[slot];
        float z = a1n + a2[(size_t)d * H + head];
        z = (z > 0.f) ? z : ALPHA * z;
        sExp[(size_t)slot * H + head] = __expf(z);
    }
}

// ---------------------------------------------------------------------------
// Edge aggregation (R6-proven structure, unchanged): 1 wave per node, lane
// owns dims lane*4..lane*4+3 (ushort4 -> full 512B row per wave-instr),
// edge loop unrolled 8-deep -> 8 row gathers in flight. 8x8 outstanding
// loads per SIMD at 8 waves/SIMD; depth-16 would halve occupancy for no
// net gain.
// ---------------------------------------------------------------------------
__global__ __launch_bounds__(256) void agg_k(
    const __half* __restrict__ h, const float* __restrict__ sExp,
    const int* __restrict__ rowStart, const int* __restrict__ colI,
    const float* __restrict__ bias, __half* __restrict__ outp, int relu, int Nn)
{
    int tid = threadIdx.x;
    int wave = tid >> 6, lane = tid & 63;
    int n = blockIdx.x * 4 + wave;
    if (n >= Nn) return;
    int head = lane >> 4;
    int s = rowStart[n], e = rowStart[n + 1];
    float ac0 = 0.f, ac1 = 0.f, ac2 = 0.f, ac3 = 0.f, den = 0.f;
    const __half* hl = h + lane * 4;

    for (int p0 = s; p0 < e; p0 += 8) {
        int d[8]; float sv[8]; ushort4 u[8];
        #pragma unroll
        for (int q = 0; q < 8; ++q) {
            int p = p0 + q;
            if (p < e) {
                d[q]  = colI[p];
                sv[q] = sExp[(size_t)p * H + head];
            }
        }
        #pragma unroll
        for (int q = 0; q < 8; ++q) {
            if (p0 + q < e)
                u[q] = *(const ushort4*)(hl + (size_t)d[q] * CDIM);
        }
        #pragma unroll
        for (int q = 0; q < 8; ++q) {
            if (p0 + q < e) {
                float svq = sv[q];
                den += svq;
                ac0 = fmaf(svq, __half2float(__ushort_as_half(u[q].x)), ac0);
                ac1 = fmaf(svq, __half2float(__ushort_as_half(u[q].y)), ac1);
                ac2 = fmaf(svq, __half2float(__ushort_as_half(u[q].z)), ac2);
                ac3 = fmaf(svq, __half2float(__ushort_as_half(u[q].w)), ac3);
            }
        }
    }

    den = (den > 0.f) ? den : 1.f;
    const float4 b4 = *(const float4*)(bias + lane * 4);
    float r0 = ac0 / den + b4.x;
    float r1 = ac1 / den + b4.y;
    float r2 = ac2 / den + b4.z;
    float r3 = ac3 / den + b4.w;
    if (relu) {
        r0 = fmaxf(r0, 0.f); r1 = fmaxf(r1, 0.f);
        r2 = fmaxf(r2, 0.f); r3 = fmaxf(r3, 0.f);
    }
    ushort4 o;
    o.x = __half_as_ushort(__float2half(r0));
    o.y = __half_as_ushort(__float2half(r1));
    o.z = __half_as_ushort(__float2half(r2));
    o.w = __half_as_ushort(__float2half(r3));
    *(ushort4*)(outp + (size_t)n * CDIM + lane * 4) = o;
}

// ---------------------------------------------------------------------------
// Classifier finalize (R8): sum the 4 per-wave partials + bias; dtype per flag.
// ---------------------------------------------------------------------------
__global__ void cls2_k(const float* __restrict__ pcls, const float* __restrict__ bcls,
                       void* __restrict__ out, int Nn, const int* __restrict__ flagp)
{
    int n = blockIdx.x * 256 + threadIdx.x;
    if (n >= Nn) return;
    const float4 p0 = *(const float4*)(pcls + (size_t)n * 16);
    const float4 p1 = *(const float4*)(pcls + (size_t)n * 16 + 4);
    const float4 p2 = *(const float4*)(pcls + (size_t)n * 16 + 8);
    const float4 p3 = *(const float4*)(pcls + (size_t)n * 16 + 12);
    float r0 = p0.x + p1.x + p2.x + p3.x + bcls[0];
    float r1 = p0.y + p1.y + p2.y + p3.y + bcls[1];
    float r2 = p0.z + p1.z + p2.z + p3.z + bcls[2];
    float r3 = p0.w + p1.w + p2.w + p3.w + bcls[3];
    if (*flagp) {
        __hip_bfloat16* o = (__hip_bfloat16*)out + (size_t)n * OUTC;
        o[0] = __float2bfloat16(r0); o[1] = __float2bfloat16(r1);
        o[2] = __float2bfloat16(r2); o[3] = __float2bfloat16(r3);
    } else {
        float* o = (float*)out + (size_t)n * OUTC;
        o[0] = r0; o[1] = r1; o[2] = r2; o[3] = r3;
    }
}

// ---------------------------------------------------------------------------
extern "C" void kernel_launch(void* const* d_in, const int* in_sizes, int n_in,
                              void* d_out, int out_size, void* d_ws, size_t ws_size,
                              hipStream_t stream)
{
    const void* x  = d_in[0];
    const int*  ei = (const int*)d_in[1];

    const int Nn = in_sizes[0] / CDIM;   // 100000
    const int Ee = in_sizes[1] / 2;      // 1600000
    const int* srcI = ei;
    const int* dstI = ei + Ee;

    char* wsp = (char*)d_ws;
    size_t off = 0;
    auto alloc = [&](size_t bytes) -> void* {
        void* p = wsp + off;
        off += (bytes + 255) & ~(size_t)255;
        return p;
    };
    __half* hA   = (__half*)alloc((size_t)Nn * CDIM * 2);  // 51.2 MB
    __half* hB   = (__half*)alloc((size_t)Nn * CDIM * 2);  // 51.2 MB
    float*  a1v       = (float*)alloc((size_t)Nn * H * 4);
    float*  a2v       = (float*)alloc((size_t)Nn * H * 4);
    float*  pcls      = (float*)alloc((size_t)Nn * 4 * OUTC * 4); // 6.4 MB
    float*  sExp      = (float*)alloc((size_t)Ee * H * 4); // 25.6 MB
    int*    rowStart  = (int*)alloc((size_t)(Nn + 1) * 4);
    int*    cursor    = (int*)alloc((size_t)Nn * 4);
    int*    colI      = (int*)alloc((size_t)Ee * 4);       // 6.4 MB
    int*    blockSums = (int*)alloc(512 * 4);
    int*    flag      = (int*)alloc(256);
    float*  wconv     = (float*)alloc((size_t)200000 * 4);
    __half* wh        = (__half*)alloc((size_t)200000 * 2);
    (void)ws_size; (void)n_in; (void)out_size;

    // dtype detect + weight conversion (proven machinery)
    detect_k<<<1, 256, 0, stream>>>((const uint32_t*)x, flag);
    WPtrs wp;
    int woff = 0;
    for (int i = 0; i < NW; ++i) {
        wp.p[i] = d_in[2 + i];
        wp.sz[i] = in_sizes[2 + i];
        wp.off[i] = woff;
        woff += in_sizes[2 + i];
    }
    {
        dim3 cgrid(256, NW);
        convert_k<<<cgrid, 256, 0, stream>>>(wp, wconv, wh, flag);
    }
    const float*  a11wf = wconv + wp.off[1];
    const float*  a11bf = wconv + wp.off[2];
    const float*  a12wf = wconv + wp.off[3];
    const float*  a12bf = wconv + wp.off[4];
    const float*  b1f   = wconv + wp.off[5];
    const float*  a21wf = wconv + wp.off[7];
    const float*  a21bf = wconv + wp.off[8];
    const float*  a22wf = wconv + wp.off[9];
    const float*  a22bf = wconv + wp.off[10];
    const float*  b2f   = wconv + wp.off[11];
    const float*  bcf   = wconv + wp.off[13];
    const float*  Wclsf = wconv + wp.off[14];
    const float*  bclsf = wconv + wp.off[15];
    const __half* W1h   = wh + wp.off[0];
    const __half* W2h   = wh + wp.off[6];
    const __half* Wch   = wh + wp.off[12];

    const int NB = (Nn + 255) / 256;   // 391 (fits scan2's 512)
    const int EB = (Ee + 255) / 256;

    // CSR build
    hipMemsetAsync(cursor, 0, (size_t)Nn * 4, stream);
    hist_k<<<EB, 256, 0, stream>>>(srcI, cursor, Ee);
    scan1_k<<<NB, 256, 0, stream>>>(cursor, blockSums, Nn);
    scan2_k<<<1, 512, 0, stream>>>(blockSums, NB);
    scan3_k<<<NB, 256, 0, stream>>>(cursor, blockSums, rowStart, cursor, Nn, Ee);
    scatter_k<<<EB, 256, 0, stream>>>(srcI, dstI, cursor, colI, Ee);

    dim3 ggrid((Nn + 127) / 128, CDIM / 128);   // (782, 2)
    const int AB = (Nn + 3) / 4;                // 4 nodes (waves) per block

    // Layer 1: gemm(raw x) -> hA (+ fused scores); escore; agg -> hB (relu)
    gemm_k<0, 1><<<ggrid, 256, 0, stream>>>(x, W1h, nullptr, hA, Nn, flag,
                                            a11wf, a11bf, a12wf, a12bf, a1v, a2v);
    escore_k<<<AB, 256, 0, stream>>>(rowStart, colI, a1v, a2v, sExp, Nn);
    agg_k<<<AB, 256, 0, stream>>>(hA, sExp, rowStart, colI, b1f, hB, 1, Nn);

    // Layer 2: gemm(hB) -> hA (+ fused scores); escore; agg -> hB
    gemm_k<1, 1><<<ggrid, 256, 0, stream>>>(hB, W2h, nullptr, hA, Nn, flag,
                                            a21wf, a21bf, a22wf, a22bf, a1v, a2v);
    escore_k<<<AB, 256, 0, stream>>>(rowStart, colI, a1v, a2v, sExp, Nn);
    agg_k<<<AB, 256, 0, stream>>>(hA, sExp, rowStart, colI, b2f, hB, 0, Nn);

    // Collator + fused classifier partials; then finalize
    gemm_k<1, 0><<<ggrid, 256, 0, stream>>>(hB, Wch, bcf, nullptr, Nn, flag,
                                            Wclsf, nullptr, nullptr, nullptr,
                                            pcls, nullptr);
    cls2_k<<<NB, 256, 0, stream>>>(pcls, bclsf, d_out, Nn, flag);
}

// Round 4
// 668.990 us; speedup vs baseline: 1.4502x; 1.2002x over previous
//
#include <hip/hip_runtime.h>
#include <hip/hip_bf16.h>
#include <hip/hip_fp16.h>
#include <stdint.h>

#define H 4
#define HID 64
#define CDIM 256   /* = H*HID = IN = FC */
#define OUTC 4
#define ALPHA 0.2f
#define NW 16      /* number of float weight inputs (d_in[2..17]) */
#define MAXB 512   /* max buckets; NBUCK = ceil(Nn/256) <= 512 for Nn <= 131072 */
#define TILE1 4096 /* edges per pass1 tile (8 per thread x 512 threads) */

typedef __attribute__((ext_vector_type(8))) _Float16 f16x8;
typedef __attribute__((ext_vector_type(4))) float f32x4;

// ---------------------------------------------------------------------------
// dtype detection (R2/R4/R5-proven; real answer on this harness: fp32, flag=0)
// ---------------------------------------------------------------------------
__global__ void detect_k(const uint32_t* __restrict__ xw, int* __restrict__ flag) {
    __shared__ int sd[256];
    int t = threadIdx.x;
    int hits = 0;
    for (int i = 0; i < 16; ++i) {
        uint32_t w = xw[t * 16 + i];
        uint32_t ex = (w >> 7) & 0xffu;
        if (ex >= 100u && ex <= 145u) hits++;
    }
    sd[t] = hits;
    __syncthreads();
    for (int s = 128; s > 0; s >>= 1) {
        if (t < s) sd[t] += sd[t + s];
        __syncthreads();
    }
    if (t == 0) *flag = (sd[0] > 3000) ? 1 : 0;
}

// ---------------------------------------------------------------------------
// Convert all 16 weight tensors to fp32 AND fp16 in ws (branch on flag).
// ---------------------------------------------------------------------------
struct WPtrs {
    const void* p[NW];
    int sz[NW];
    int off[NW];
};

__global__ void convert_k(WPtrs ptrs, float* __restrict__ outf, __half* __restrict__ outh,
                          const int* __restrict__ flag) {
    int which = blockIdx.y;
    int n = ptrs.sz[which];
    int i = blockIdx.x * 256 + threadIdx.x;
    if (i >= n) return;
    float v;
    if (*flag) v = __bfloat162float(((const __hip_bfloat16*)ptrs.p[which])[i]);
    else       v = ((const float*)ptrs.p[which])[i];
    outf[ptrs.off[which] + i] = v;
    outh[ptrs.off[which] + i] = __float2half(v);
}

// ---------------------------------------------------------------------------
// CSR build, R9 rewrite: two-level binning. Old pipeline (hist + 3 scans +
// scatter) was random-access-bound: 1.6M random 4B atomics + 1.6M random 4B
// stores = 125us at 900 GB/s effective (each store dirties a private line;
// cross-XCD partial-line write-through). New pipeline: every global access
// dense, global atomics only on 391 hot bucket cursors.
//   bhist_k: LDS-privatized bucket (src>>8) histogram.
//   bscan_k: one-block scan -> bucketStart / bucketCur; rowStart[Nn]=Ee.
//   pass1_k: per-4096-edge tile, counting-sort by bucket in LDS (edges in
//            registers, packed (dst<<8)|(src&255); valid for Nn < 2^24),
//            one global atomicAdd per (tile,bucket) to reserve, contiguous
//            coalesced copy-out per bucket run.
//   pass2_k: one block per bucket: node counts + scan in LDS (emits rowStart
//            -- node-level hist/scan kernels deleted), then LDS-cursor
//            placement into colI. Each bucket's 16KB colI window is written
//            by exactly one block/XCD -> full lines, zero global atomics.
// ---------------------------------------------------------------------------
__global__ __launch_bounds__(512) void bhist_k(const int* __restrict__ srcI,
                                               int* __restrict__ bucketCnt,
                                               int Ee, int nbuck)
{
    __shared__ int bc[MAXB];
    int t = threadIdx.x;
    bc[t] = 0;
    __syncthreads();
    int base = blockIdx.x * TILE1;
    #pragma unroll
    for (int q = 0; q < 8; ++q) {
        int i = base + q * 512 + t;
        if (i < Ee) atomicAdd(&bc[srcI[i] >> 8], 1);
    }
    __syncthreads();
    if (t < nbuck && bc[t] > 0) atomicAdd(&bucketCnt[t], bc[t]);
}

__global__ __launch_bounds__(512) void bscan_k(
    const int* __restrict__ bucketCnt, int* __restrict__ bucketCur,
    int* __restrict__ bucketStart, int* __restrict__ rowStart,
    int nbuck, int Nn, int Ee)
{
    __shared__ int sd[MAXB];
    int t = threadIdx.x;
    int v = (t < nbuck) ? bucketCnt[t] : 0;
    sd[t] = v;
    __syncthreads();
    for (int off = 1; off < MAXB; off <<= 1) {
        int add = (t >= off) ? sd[t - off] : 0;
        __syncthreads();
        sd[t] += add;
        __syncthreads();
    }
    if (t < nbuck) {
        int excl = sd[t] - v;
        bucketCur[t] = excl;
        bucketStart[t] = excl;
    }
    if (t == 0) { bucketStart[nbuck] = Ee; rowStart[Nn] = Ee; }
}

__global__ __launch_bounds__(512) void pass1_k(
    const int* __restrict__ srcI, const int* __restrict__ dstI,
    int* __restrict__ bucketCur, uint32_t* __restrict__ pairs,
    int Ee, int nbuck)
{
    __shared__ int cntL[MAXB], scanL[MAXB], exclL[MAXB], curL[MAXB], gbaseL[MAXB];
    __shared__ uint32_t sortedV[TILE1];
    __shared__ uint16_t sortedB[TILE1];
    const int t = threadIdx.x;
    const int base = blockIdx.x * TILE1;
    cntL[t] = 0;
    __syncthreads();
    uint32_t vq[8]; int bq[8];
    #pragma unroll
    for (int q = 0; q < 8; ++q) {
        int i = base + q * 512 + t;
        if (i < Ee) {
            int s = srcI[i], d = dstI[i];
            bq[q] = s >> 8;
            vq[q] = ((uint32_t)d << 8) | (uint32_t)(s & 255);
            atomicAdd(&cntL[bq[q]], 1);
        } else bq[q] = -1;
    }
    __syncthreads();
    scanL[t] = cntL[t];
    __syncthreads();
    for (int off = 1; off < MAXB; off <<= 1) {
        int add = (t >= off) ? scanL[t - off] : 0;
        __syncthreads();
        scanL[t] += add;
        __syncthreads();
    }
    int excl = scanL[t] - cntL[t];
    exclL[t] = excl;
    curL[t] = excl;
    if (t < nbuck && cntL[t] > 0)
        gbaseL[t] = atomicAdd(&bucketCur[t], cntL[t]);
    __syncthreads();
    #pragma unroll
    for (int q = 0; q < 8; ++q) {
        if (bq[q] >= 0) {
            int pos = atomicAdd(&curL[bq[q]], 1);
            sortedV[pos] = vq[q];
            sortedB[pos] = (uint16_t)bq[q];
        }
    }
    __syncthreads();
    int tcount = min(TILE1, Ee - base);
    for (int j = t; j < tcount; j += 512) {
        int b = sortedB[j];
        pairs[gbaseL[b] + (j - exclL[b])] = sortedV[j];
    }
}

__global__ __launch_bounds__(256) void pass2_k(
    const uint32_t* __restrict__ pairs, const int* __restrict__ bucketStart,
    int* __restrict__ rowStart, int* __restrict__ colI, int Nn)
{
    __shared__ int ncnt[256], sd[256], lcur[256];
    int b = blockIdx.x, t = threadIdx.x;
    int n0 = b << 8;
    int s = bucketStart[b], e = bucketStart[b + 1];
    ncnt[t] = 0;
    __syncthreads();
    for (int p = s + t; p < e; p += 256)
        atomicAdd(&ncnt[pairs[p] & 255], 1);
    __syncthreads();
    int v = ncnt[t];
    sd[t] = v;
    __syncthreads();
    for (int off = 1; off < 256; off <<= 1) {
        int add = (t >= off) ? sd[t - off] : 0;
        __syncthreads();
        sd[t] += add;
        __syncthreads();
    }
    int start = s + sd[t] - v;
    lcur[t] = start;
    if (n0 + t < Nn) rowStart[n0 + t] = start;
    __syncthreads();
    for (int p = s + t; p < e; p += 256) {
        uint32_t pv = pairs[p];
        int q = atomicAdd(&lcur[pv & 255], 1);
        colI[q] = (int)(pv >> 8);
    }
}

// ---------------------------------------------------------------------------
// f16 MFMA GEMM, 128x128 tile / 4 waves, BK=32, mfma_f32_16x16x32_f16.
// AMODE 0: A = raw x (fp32 or bf16 per *flag), convert to fp16 in staging.
// AMODE 1: A = fp16 n-major [M][256].
// OMODE 0: collator + FUSED classifier (R8): per-wave 64-col partial logits,
//          slot = blockIdx.y*2 + (wave>>1) (4 distinct slots per row).
// OMODE 1: fp16 n-major out [M][256] (pre-relu, no bias) + fused attention
//          scores a1v/a2v[n][head].
// ---------------------------------------------------------------------------
template <int AMODE, int OMODE>
__global__ __launch_bounds__(256) void gemm_k(
    const void* __restrict__ Ap, const __half* __restrict__ B,
    const float* __restrict__ bias, void* __restrict__ Cp, int M,
    const int* __restrict__ flagp,
    const float* __restrict__ a1w, const float* __restrict__ a1b,
    const float* __restrict__ a2w, const float* __restrict__ a2b,
    float* __restrict__ a1v, float* __restrict__ a2v)
{
    __shared__ __align__(16) char smem[128 * 136 * 2];   // 34.8 KB
    short* As = (short*)smem;              // 128*40 shorts
    short* Bs = (short*)(smem + 10240);
    const int tid  = threadIdx.x;
    const int row0 = blockIdx.x * 128;
    const int col0 = blockIdx.y * 128;
    const int wave = tid >> 6, lane = tid & 63;
    const int m0w = (wave & 1) * 64;
    const int n0w = (wave >> 1) * 64;
    const int lm = lane & 15, lg = lane >> 4;
    const int isbf = (AMODE == 0) ? *flagp : 0;

    f32x4 acc[4][4] = {};

    for (int k0 = 0; k0 < CDIM; k0 += 32) {
        #pragma unroll
        for (int l = 0; l < 2; ++l) {
            int c = tid + l * 256;
            int m = c >> 2, kc = c & 3;
            int gr = row0 + m;
            uint4 q = make_uint4(0u, 0u, 0u, 0u);
            if constexpr (AMODE == 1) {
                const __half* A = (const __half*)Ap;
                if (gr < M) q = *(const uint4*)(A + (size_t)gr * CDIM + k0 + kc * 8);
            } else {
                if (gr < M) {
                    __half hv[8];
                    if (isbf) {
                        const uint4 qb = *(const uint4*)((const __hip_bfloat16*)Ap
                                           + (size_t)gr * CDIM + k0 + kc * 8);
                        const uint32_t* w = (const uint32_t*)&qb;
                        #pragma unroll
                        for (int p = 0; p < 4; ++p) {
                            hv[2*p]   = __float2half(__uint_as_float((w[p] & 0xffffu) << 16));
                            hv[2*p+1] = __float2half(__uint_as_float(w[p] & 0xffff0000u));
                        }
                    } else {
                        const float* A = (const float*)Ap + (size_t)gr * CDIM + k0 + kc * 8;
                        const float4 f0 = *(const float4*)A;
                        const float4 f1 = *(const float4*)(A + 4);
                        hv[0]=__float2half(f0.x); hv[1]=__float2half(f0.y);
                        hv[2]=__float2half(f0.z); hv[3]=__float2half(f0.w);
                        hv[4]=__float2half(f1.x); hv[5]=__float2half(f1.y);
                        hv[6]=__float2half(f1.z); hv[7]=__float2half(f1.w);
                    }
                    q = *(uint4*)hv;
                }
            }
            *(uint4*)(&As[m * 40 + kc * 8]) = q;
        }
        #pragma unroll
        for (int l = 0; l < 2; ++l) {
            int c = tid + l * 256;
            int nn = c >> 2, kc = c & 3;
            uint4 q = *(const uint4*)(B + (size_t)(col0 + nn) * CDIM + k0 + kc * 8);
            *(uint4*)(&Bs[nn * 40 + kc * 8]) = q;
        }
        __syncthreads();
        f16x8 af[4], bfr[4];
        #pragma unroll
        for (int i = 0; i < 4; ++i)
            af[i] = *(f16x8*)(&As[(m0w + i * 16 + lm) * 40 + lg * 8]);
        #pragma unroll
        for (int j = 0; j < 4; ++j)
            bfr[j] = *(f16x8*)(&Bs[(n0w + j * 16 + lm) * 40 + lg * 8]);
        #pragma unroll
        for (int i = 0; i < 4; ++i)
            #pragma unroll
            for (int j = 0; j < 4; ++j)
                acc[i][j] = __builtin_amdgcn_mfma_f32_16x16x32_f16(
                    af[i], bfr[j], acc[i][j], 0, 0, 0);
        __syncthreads();
    }

    if constexpr (OMODE == 1) {
        // fp16 tile -> LDS; n-major coalesced stores + fused scores
        __half (*Cs)[136] = (__half(*)[136])smem;
        #pragma unroll
        for (int i = 0; i < 4; ++i)
            #pragma unroll
            for (int r = 0; r < 4; ++r) {
                int lr = m0w + i * 16 + lg * 4 + r;
                #pragma unroll
                for (int j = 0; j < 4; ++j)
                    Cs[lr][n0w + j * 16 + lm] = __float2half(acc[i][j][r]);
            }
        __syncthreads();
        __half* C = (__half*)Cp;
        #pragma unroll
        for (int l = 0; l < 8; ++l) {
            int c = tid + l * 256;
            int rr = c >> 4, cc = c & 15;
            int gr = row0 + rr;
            if (gr < M)
                *(uint4*)(C + (size_t)gr * CDIM + col0 + cc * 8) = *(uint4*)(&Cs[rr][cc * 8]);
        }
        // fused scores: thread t -> (row t>>1, head-sel t&1); block covers 2 heads
        {
            int row = tid >> 1, hsel = tid & 1;
            int gr = row0 + row;
            if (gr < M) {
                int ghead = (col0 >> 6) + hsel;
                const float* w1 = a1w + ghead * 64;
                const float* w2 = a2w + ghead * 64;
                const uint* cp = (const uint*)&Cs[row][hsel * 64];
                float s1 = 0.f, s2 = 0.f;
                #pragma unroll
                for (int j = 0; j < 32; ++j) {
                    uint u = cp[j];
                    float2 f = __half22float2(*(__half2*)&u);
                    s1 += f.x * w1[2*j] + f.y * w1[2*j+1];
                    s2 += f.x * w2[2*j] + f.y * w2[2*j+1];
                }
                a1v[(size_t)gr * H + ghead] = s1 + a1b[ghead];
                a2v[(size_t)gr * H + ghead] = s2 + a2b[ghead];
            }
        }
    } else {
        // collator + fused classifier partials (R8). feat stays in registers.
        const float* Wc4 = a1w;     // Wcls [OUTC][CDIM] fp32
        float* pcls = a1v;          // [M][4][OUTC] partials
        const int slot = blockIdx.y * 2 + (wave >> 1);
        float wv[OUTC][4];
        #pragma unroll
        for (int o = 0; o < OUTC; ++o)
            #pragma unroll
            for (int j = 0; j < 4; ++j)
                wv[o][j] = Wc4[o * CDIM + col0 + n0w + j * 16 + lm];
        #pragma unroll
        for (int i = 0; i < 4; ++i)
            #pragma unroll
            for (int r = 0; r < 4; ++r) {
                int grow = row0 + m0w + i * 16 + lg * 4 + r;
                if (grow < M) {
                    float po[OUTC] = {0.f, 0.f, 0.f, 0.f};
                    #pragma unroll
                    for (int j = 0; j < 4; ++j) {
                        int gcol = col0 + n0w + j * 16 + lm;
                        float t = fmaxf(acc[i][j][r] + bias[gcol], 0.f);
                        #pragma unroll
                        for (int o = 0; o < OUTC; ++o)
                            po[o] = fmaf(t, wv[o][j], po[o]);
                    }
                    // reduce over the 16 lanes (lm) sharing this row
                    #pragma unroll
                    for (int m = 1; m < 16; m <<= 1)
                        #pragma unroll
                        for (int o = 0; o < OUTC; ++o)
                            po[o] += __shfl_xor(po[o], m);
                    if (lm < OUTC) {
                        float v = (lm == 0) ? po[0] : (lm == 1) ? po[1]
                                : (lm == 2) ? po[2] : po[3];
                        pcls[((size_t)grow * 4 + slot) * OUTC + lm] = v;
                    }
                }
            }
        (void)Cp;
    }
}

// ---------------------------------------------------------------------------
// Edge scores, per-node (R7): one wave per node; src = n implicitly.
// ---------------------------------------------------------------------------
__global__ __launch_bounds__(256) void escore_k(
    const int* __restrict__ rowStart, const int* __restrict__ colI,
    const float* __restrict__ a1, const float* __restrict__ a2,
    float* __restrict__ sExp, int Nn)
{
    int tid = threadIdx.x;
    int wave = tid >> 6, lane = tid & 63;
    int n = blockIdx.x * 4 + wave;
    if (n >= Nn) return;
    int head = lane & 3;
    int s = rowStart[n], e = rowStart[n + 1];
    float a1n = a1[(size_t)n * H + head];
    for (int idx = lane; ; idx += 64) {
        int slot = s + (idx >> 2);
        if (slot >= e) break;
        int d = colI[slot];
        float z = a1n + a2[(size_t)d * H + head];
        z = (z > 0.f) ? z : ALPHA * z;
        sExp[(size_t)slot * H + head] = __expf(z);
    }
}

// ---------------------------------------------------------------------------
// Edge aggregation (R6-proven structure, unchanged): 1 wave per node, lane
// owns dims lane*4..lane*4+3, edge loop unrolled 8-deep -> 8 gathers in
// flight.
// ---------------------------------------------------------------------------
__global__ __launch_bounds__(256) void agg_k(
    const __half* __restrict__ h, const float* __restrict__ sExp,
    const int* __restrict__ rowStart, const int* __restrict__ colI,
    const float* __restrict__ bias, __half* __restrict__ outp, int relu, int Nn)
{
    int tid = threadIdx.x;
    int wave = tid >> 6, lane = tid & 63;
    int n = blockIdx.x * 4 + wave;
    if (n >= Nn) return;
    int head = lane >> 4;
    int s = rowStart[n], e = rowStart[n + 1];
    float ac0 = 0.f, ac1 = 0.f, ac2 = 0.f, ac3 = 0.f, den = 0.f;
    const __half* hl = h + lane * 4;

    for (int p0 = s; p0 < e; p0 += 8) {
        int d[8]; float sv[8]; ushort4 u[8];
        #pragma unroll
        for (int q = 0; q < 8; ++q) {
            int p = p0 + q;
            if (p < e) {
                d[q]  = colI[p];
                sv[q] = sExp[(size_t)p * H + head];
            }
        }
        #pragma unroll
        for (int q = 0; q < 8; ++q) {
            if (p0 + q < e)
                u[q] = *(const ushort4*)(hl + (size_t)d[q] * CDIM);
        }
        #pragma unroll
        for (int q = 0; q < 8; ++q) {
            if (p0 + q < e) {
                float svq = sv[q];
                den += svq;
                ac0 = fmaf(svq, __half2float(__ushort_as_half(u[q].x)), ac0);
                ac1 = fmaf(svq, __half2float(__ushort_as_half(u[q].y)), ac1);
                ac2 = fmaf(svq, __half2float(__ushort_as_half(u[q].z)), ac2);
                ac3 = fmaf(svq, __half2float(__ushort_as_half(u[q].w)), ac3);
            }
        }
    }

    den = (den > 0.f) ? den : 1.f;
    const float4 b4 = *(const float4*)(bias + lane * 4);
    float r0 = ac0 / den + b4.x;
    float r1 = ac1 / den + b4.y;
    float r2 = ac2 / den + b4.z;
    float r3 = ac3 / den + b4.w;
    if (relu) {
        r0 = fmaxf(r0, 0.f); r1 = fmaxf(r1, 0.f);
        r2 = fmaxf(r2, 0.f); r3 = fmaxf(r3, 0.f);
    }
    ushort4 o;
    o.x = __half_as_ushort(__float2half(r0));
    o.y = __half_as_ushort(__float2half(r1));
    o.z = __half_as_ushort(__float2half(r2));
    o.w = __half_as_ushort(__float2half(r3));
    *(ushort4*)(outp + (size_t)n * CDIM + lane * 4) = o;
}

// ---------------------------------------------------------------------------
// Classifier finalize (R8): sum the 4 per-wave partials + bias; dtype per flag.
// ---------------------------------------------------------------------------
__global__ void cls2_k(const float* __restrict__ pcls, const float* __restrict__ bcls,
                       void* __restrict__ out, int Nn, const int* __restrict__ flagp)
{
    int n = blockIdx.x * 256 + threadIdx.x;
    if (n >= Nn) return;
    const float4 p0 = *(const float4*)(pcls + (size_t)n * 16);
    const float4 p1 = *(const float4*)(pcls + (size_t)n * 16 + 4);
    const float4 p2 = *(const float4*)(pcls + (size_t)n * 16 + 8);
    const float4 p3 = *(const float4*)(pcls + (size_t)n * 16 + 12);
    float r0 = p0.x + p1.x + p2.x + p3.x + bcls[0];
    float r1 = p0.y + p1.y + p2.y + p3.y + bcls[1];
    float r2 = p0.z + p1.z + p2.z + p3.z + bcls[2];
    float r3 = p0.w + p1.w + p2.w + p3.w + bcls[3];
    if (*flagp) {
        __hip_bfloat16* o = (__hip_bfloat16*)out + (size_t)n * OUTC;
        o[0] = __float2bfloat16(r0); o[1] = __float2bfloat16(r1);
        o[2] = __float2bfloat16(r2); o[3] = __float2bfloat16(r3);
    } else {
        float* o = (float*)out + (size_t)n * OUTC;
        o[0] = r0; o[1] = r1; o[2] = r2; o[3] = r3;
    }
}

// ---------------------------------------------------------------------------
extern "C" void kernel_launch(void* const* d_in, const int* in_sizes, int n_in,
                              void* d_out, int out_size, void* d_ws, size_t ws_size,
                              hipStream_t stream)
{
    const void* x  = d_in[0];
    const int*  ei = (const int*)d_in[1];

    const int Nn = in_sizes[0] / CDIM;   // 100000
    const int Ee = in_sizes[1] / 2;      // 1600000
    const int* srcI = ei;
    const int* dstI = ei + Ee;

    char* wsp = (char*)d_ws;
    size_t off = 0;
    auto alloc = [&](size_t bytes) -> void* {
        void* p = wsp + off;
        off += (bytes + 255) & ~(size_t)255;
        return p;
    };
    __half* hA   = (__half*)alloc((size_t)Nn * CDIM * 2);  // 51.2 MB
    __half* hB   = (__half*)alloc((size_t)Nn * CDIM * 2);  // 51.2 MB
    float*  a1v       = (float*)alloc((size_t)Nn * H * 4);
    float*  a2v       = (float*)alloc((size_t)Nn * H * 4);
    float*  pcls      = (float*)alloc((size_t)Nn * 4 * OUTC * 4); // 6.4 MB
    float*  sExp      = (float*)alloc((size_t)Ee * H * 4); // 25.6 MB
    int*    rowStart  = (int*)alloc((size_t)(Nn + 1) * 4);
    int*    colI      = (int*)alloc((size_t)Ee * 4);       // 6.4 MB
    uint32_t* pairs   = (uint32_t*)alloc((size_t)Ee * 4);  // 6.4 MB packed
    int*    bucketCnt   = (int*)alloc(MAXB * 4);
    int*    bucketCur   = (int*)alloc(MAXB * 4);
    int*    bucketStart = (int*)alloc((MAXB + 1) * 4);
    int*    flag      = (int*)alloc(256);
    float*  wconv     = (float*)alloc((size_t)200000 * 4);
    __half* wh        = (__half*)alloc((size_t)200000 * 2);
    (void)ws_size; (void)n_in; (void)out_size;

    // dtype detect + weight conversion (proven machinery)
    detect_k<<<1, 256, 0, stream>>>((const uint32_t*)x, flag);
    WPtrs wp;
    int woff = 0;
    for (int i = 0; i < NW; ++i) {
        wp.p[i] = d_in[2 + i];
        wp.sz[i] = in_sizes[2 + i];
        wp.off[i] = woff;
        woff += in_sizes[2 + i];
    }
    {
        dim3 cgrid(256, NW);
        convert_k<<<cgrid, 256, 0, stream>>>(wp, wconv, wh, flag);
    }
    const float*  a11wf = wconv + wp.off[1];
    const float*  a11bf = wconv + wp.off[2];
    const float*  a12wf = wconv + wp.off[3];
    const float*  a12bf = wconv + wp.off[4];
    const float*  b1f   = wconv + wp.off[5];
    const float*  a21wf = wconv + wp.off[7];
    const float*  a21bf = wconv + wp.off[8];
    const float*  a22wf = wconv + wp.off[9];
    const float*  a22bf = wconv + wp.off[10];
    const float*  b2f   = wconv + wp.off[11];
    const float*  bcf   = wconv + wp.off[13];
    const float*  Wclsf = wconv + wp.off[14];
    const float*  bclsf = wconv + wp.off[15];
    const __half* W1h   = wh + wp.off[0];
    const __half* W2h   = wh + wp.off[6];
    const __half* Wch   = wh + wp.off[12];

    const int NB = (Nn + 255) / 256;          // node blocks (391)
    const int NBUCK = (Nn + 255) >> 8;        // buckets (391, <= MAXB)
    const int TB = (Ee + TILE1 - 1) / TILE1;  // edge tiles (391)

    // CSR build (R9 binning pipeline)
    hipMemsetAsync(bucketCnt, 0, MAXB * 4, stream);
    bhist_k<<<TB, 512, 0, stream>>>(srcI, bucketCnt, Ee, NBUCK);
    bscan_k<<<1, 512, 0, stream>>>(bucketCnt, bucketCur, bucketStart, rowStart,
                                   NBUCK, Nn, Ee);
    pass1_k<<<TB, 512, 0, stream>>>(srcI, dstI, bucketCur, pairs, Ee, NBUCK);
    pass2_k<<<NBUCK, 256, 0, stream>>>(pairs, bucketStart, rowStart, colI, Nn);

    dim3 ggrid((Nn + 127) / 128, CDIM / 128);   // (782, 2)
    const int AB = (Nn + 3) / 4;                // 4 nodes (waves) per block

    // Layer 1: gemm(raw x) -> hA (+ fused scores); escore; agg -> hB (relu)
    gemm_k<0, 1><<<ggrid, 256, 0, stream>>>(x, W1h, nullptr, hA, Nn, flag,
                                            a11wf, a11bf, a12wf, a12bf, a1v, a2v);
    escore_k<<<AB, 256, 0, stream>>>(rowStart, colI, a1v, a2v, sExp, Nn);
    agg_k<<<AB, 256, 0, stream>>>(hA, sExp, rowStart, colI, b1f, hB, 1, Nn);

    // Layer 2: gemm(hB) -> hA (+ fused scores); escore; agg -> hB
    gemm_k<1, 1><<<ggrid, 256, 0, stream>>>(hB, W2h, nullptr, hA, Nn, flag,
                                            a21wf, a21bf, a22wf, a22bf, a1v, a2v);
    escore_k<<<AB, 256, 0, stream>>>(rowStart, colI, a1v, a2v, sExp, Nn);
    agg_k<<<AB, 256, 0, stream>>>(hA, sExp, rowStart, colI, b2f, hB, 0, Nn);

    // Collator + fused classifier partials; then finalize
    gemm_k<1, 0><<<ggrid, 256, 0, stream>>>(hB, Wch, bcf, nullptr, Nn, flag,
                                            Wclsf, nullptr, nullptr, nullptr,
                                            pcls, nullptr);
    cls2_k<<<NB, 256, 0, stream>>>(pcls, bclsf, d_out, Nn, flag);
}

// Round 5
// 651.424 us; speedup vs baseline: 1.4893x; 1.0270x over previous
//
#include <hip/hip_runtime.h>
#include <hip/hip_bf16.h>
#include <hip/hip_fp16.h>
#include <stdint.h>

#define H 4
#define HID 64
#define CDIM 256   /* = H*HID = IN = FC */
#define OUTC 4
#define ALPHA 0.2f
#define NW 16      /* number of float weight inputs (d_in[2..17]) */
#define MAXB 512   /* max buckets; NBUCK = ceil(Nn/256) <= 512 for Nn <= 131072 */
#define TILE1 4096 /* edges per pass1 tile (8 per thread x 512 threads) */

typedef __attribute__((ext_vector_type(8))) _Float16 f16x8;
typedef __attribute__((ext_vector_type(4))) float f32x4;

// ---------------------------------------------------------------------------
// dtype detection (R2/R4/R5-proven; real answer on this harness: fp32, flag=0)
// ---------------------------------------------------------------------------
__global__ void detect_k(const uint32_t* __restrict__ xw, int* __restrict__ flag) {
    __shared__ int sd[256];
    int t = threadIdx.x;
    int hits = 0;
    for (int i = 0; i < 16; ++i) {
        uint32_t w = xw[t * 16 + i];
        uint32_t ex = (w >> 7) & 0xffu;
        if (ex >= 100u && ex <= 145u) hits++;
    }
    sd[t] = hits;
    __syncthreads();
    for (int s = 128; s > 0; s >>= 1) {
        if (t < s) sd[t] += sd[t + s];
        __syncthreads();
    }
    if (t == 0) *flag = (sd[0] > 3000) ? 1 : 0;
}

// ---------------------------------------------------------------------------
// Convert all 16 weight tensors to fp32 AND fp16 in ws (branch on flag).
// ---------------------------------------------------------------------------
struct WPtrs {
    const void* p[NW];
    int sz[NW];
    int off[NW];
};

__global__ void convert_k(WPtrs ptrs, float* __restrict__ outf, __half* __restrict__ outh,
                          const int* __restrict__ flag) {
    int which = blockIdx.y;
    int n = ptrs.sz[which];
    int i = blockIdx.x * 256 + threadIdx.x;
    if (i >= n) return;
    float v;
    if (*flag) v = __bfloat162float(((const __hip_bfloat16*)ptrs.p[which])[i]);
    else       v = ((const float*)ptrs.p[which])[i];
    outf[ptrs.off[which] + i] = v;
    outh[ptrs.off[which] + i] = __float2half(v);
}

// ---------------------------------------------------------------------------
// CSR build, R9 binning pipeline (R4-proven: dense accesses, no global
// random atomics; replaced the 125us scatter).
// ---------------------------------------------------------------------------
__global__ __launch_bounds__(512) void bhist_k(const int* __restrict__ srcI,
                                               int* __restrict__ bucketCnt,
                                               int Ee, int nbuck)
{
    __shared__ int bc[MAXB];
    int t = threadIdx.x;
    bc[t] = 0;
    __syncthreads();
    int base = blockIdx.x * TILE1;
    #pragma unroll
    for (int q = 0; q < 8; ++q) {
        int i = base + q * 512 + t;
        if (i < Ee) atomicAdd(&bc[srcI[i] >> 8], 1);
    }
    __syncthreads();
    if (t < nbuck && bc[t] > 0) atomicAdd(&bucketCnt[t], bc[t]);
}

__global__ __launch_bounds__(512) void bscan_k(
    const int* __restrict__ bucketCnt, int* __restrict__ bucketCur,
    int* __restrict__ bucketStart, int* __restrict__ rowStart,
    int nbuck, int Nn, int Ee)
{
    __shared__ int sd[MAXB];
    int t = threadIdx.x;
    int v = (t < nbuck) ? bucketCnt[t] : 0;
    sd[t] = v;
    __syncthreads();
    for (int off = 1; off < MAXB; off <<= 1) {
        int add = (t >= off) ? sd[t - off] : 0;
        __syncthreads();
        sd[t] += add;
        __syncthreads();
    }
    if (t < nbuck) {
        int excl = sd[t] - v;
        bucketCur[t] = excl;
        bucketStart[t] = excl;
    }
    if (t == 0) { bucketStart[nbuck] = Ee; rowStart[Nn] = Ee; }
}

__global__ __launch_bounds__(512) void pass1_k(
    const int* __restrict__ srcI, const int* __restrict__ dstI,
    int* __restrict__ bucketCur, uint32_t* __restrict__ pairs,
    int Ee, int nbuck)
{
    __shared__ int cntL[MAXB], scanL[MAXB], exclL[MAXB], curL[MAXB], gbaseL[MAXB];
    __shared__ uint32_t sortedV[TILE1];
    __shared__ uint16_t sortedB[TILE1];
    const int t = threadIdx.x;
    const int base = blockIdx.x * TILE1;
    cntL[t] = 0;
    __syncthreads();
    uint32_t vq[8]; int bq[8];
    #pragma unroll
    for (int q = 0; q < 8; ++q) {
        int i = base + q * 512 + t;
        if (i < Ee) {
            int s = srcI[i], d = dstI[i];
            bq[q] = s >> 8;
            vq[q] = ((uint32_t)d << 8) | (uint32_t)(s & 255);
            atomicAdd(&cntL[bq[q]], 1);
        } else bq[q] = -1;
    }
    __syncthreads();
    scanL[t] = cntL[t];
    __syncthreads();
    for (int off = 1; off < MAXB; off <<= 1) {
        int add = (t >= off) ? scanL[t - off] : 0;
        __syncthreads();
        scanL[t] += add;
        __syncthreads();
    }
    int excl = scanL[t] - cntL[t];
    exclL[t] = excl;
    curL[t] = excl;
    if (t < nbuck && cntL[t] > 0)
        gbaseL[t] = atomicAdd(&bucketCur[t], cntL[t]);
    __syncthreads();
    #pragma unroll
    for (int q = 0; q < 8; ++q) {
        if (bq[q] >= 0) {
            int pos = atomicAdd(&curL[bq[q]], 1);
            sortedV[pos] = vq[q];
            sortedB[pos] = (uint16_t)bq[q];
        }
    }
    __syncthreads();
    int tcount = min(TILE1, Ee - base);
    for (int j = t; j < tcount; j += 512) {
        int b = sortedB[j];
        pairs[gbaseL[b] + (j - exclL[b])] = sortedV[j];
    }
}

__global__ __launch_bounds__(256) void pass2_k(
    const uint32_t* __restrict__ pairs, const int* __restrict__ bucketStart,
    int* __restrict__ rowStart, int* __restrict__ colI, int Nn)
{
    __shared__ int ncnt[256], sd[256], lcur[256];
    int b = blockIdx.x, t = threadIdx.x;
    int n0 = b << 8;
    int s = bucketStart[b], e = bucketStart[b + 1];
    ncnt[t] = 0;
    __syncthreads();
    for (int p = s + t; p < e; p += 256)
        atomicAdd(&ncnt[pairs[p] & 255], 1);
    __syncthreads();
    int v = ncnt[t];
    sd[t] = v;
    __syncthreads();
    for (int off = 1; off < 256; off <<= 1) {
        int add = (t >= off) ? sd[t - off] : 0;
        __syncthreads();
        sd[t] += add;
        __syncthreads();
    }
    int start = s + sd[t] - v;
    lcur[t] = start;
    if (n0 + t < Nn) rowStart[n0 + t] = start;
    __syncthreads();
    for (int p = s + t; p < e; p += 256) {
        uint32_t pv = pairs[p];
        int q = atomicAdd(&lcur[pv & 255], 1);
        colI[q] = (int)(pv >> 8);
    }
}

// ---------------------------------------------------------------------------
// f16 MFMA GEMM, 128x128 tile / 4 waves, BK=32, mfma_f32_16x16x32_f16.
// AMODE 0: A = raw x (fp32 or bf16 per *flag), convert to fp16 in staging.
// AMODE 1: A = fp16 n-major [M][256].
// OMODE 0: collator + FUSED classifier (R8): per-wave 64-col partial logits,
//          slot = blockIdx.y*2 + (wave>>1) (4 distinct slots per row).
// OMODE 1: fp16 n-major out [M][256] (pre-relu, no bias) + fused attention
//          scores a1v/a2v[n][head].
// ---------------------------------------------------------------------------
template <int AMODE, int OMODE>
__global__ __launch_bounds__(256) void gemm_k(
    const void* __restrict__ Ap, const __half* __restrict__ B,
    const float* __restrict__ bias, void* __restrict__ Cp, int M,
    const int* __restrict__ flagp,
    const float* __restrict__ a1w, const float* __restrict__ a1b,
    const float* __restrict__ a2w, const float* __restrict__ a2b,
    float* __restrict__ a1v, float* __restrict__ a2v)
{
    __shared__ __align__(16) char smem[128 * 136 * 2];   // 34.8 KB
    short* As = (short*)smem;              // 128*40 shorts
    short* Bs = (short*)(smem + 10240);
    const int tid  = threadIdx.x;
    const int row0 = blockIdx.x * 128;
    const int col0 = blockIdx.y * 128;
    const int wave = tid >> 6, lane = tid & 63;
    const int m0w = (wave & 1) * 64;
    const int n0w = (wave >> 1) * 64;
    const int lm = lane & 15, lg = lane >> 4;
    const int isbf = (AMODE == 0) ? *flagp : 0;

    f32x4 acc[4][4] = {};

    for (int k0 = 0; k0 < CDIM; k0 += 32) {
        #pragma unroll
        for (int l = 0; l < 2; ++l) {
            int c = tid + l * 256;
            int m = c >> 2, kc = c & 3;
            int gr = row0 + m;
            uint4 q = make_uint4(0u, 0u, 0u, 0u);
            if constexpr (AMODE == 1) {
                const __half* A = (const __half*)Ap;
                if (gr < M) q = *(const uint4*)(A + (size_t)gr * CDIM + k0 + kc * 8);
            } else {
                if (gr < M) {
                    __half hv[8];
                    if (isbf) {
                        const uint4 qb = *(const uint4*)((const __hip_bfloat16*)Ap
                                           + (size_t)gr * CDIM + k0 + kc * 8);
                        const uint32_t* w = (const uint32_t*)&qb;
                        #pragma unroll
                        for (int p = 0; p < 4; ++p) {
                            hv[2*p]   = __float2half(__uint_as_float((w[p] & 0xffffu) << 16));
                            hv[2*p+1] = __float2half(__uint_as_float(w[p] & 0xffff0000u));
                        }
                    } else {
                        const float* A = (const float*)Ap + (size_t)gr * CDIM + k0 + kc * 8;
                        const float4 f0 = *(const float4*)A;
                        const float4 f1 = *(const float4*)(A + 4);
                        hv[0]=__float2half(f0.x); hv[1]=__float2half(f0.y);
                        hv[2]=__float2half(f0.z); hv[3]=__float2half(f0.w);
                        hv[4]=__float2half(f1.x); hv[5]=__float2half(f1.y);
                        hv[6]=__float2half(f1.z); hv[7]=__float2half(f1.w);
                    }
                    q = *(uint4*)hv;
                }
            }
            *(uint4*)(&As[m * 40 + kc * 8]) = q;
        }
        #pragma unroll
        for (int l = 0; l < 2; ++l) {
            int c = tid + l * 256;
            int nn = c >> 2, kc = c & 3;
            uint4 q = *(const uint4*)(B + (size_t)(col0 + nn) * CDIM + k0 + kc * 8);
            *(uint4*)(&Bs[nn * 40 + kc * 8]) = q;
        }
        __syncthreads();
        f16x8 af[4], bfr[4];
        #pragma unroll
        for (int i = 0; i < 4; ++i)
            af[i] = *(f16x8*)(&As[(m0w + i * 16 + lm) * 40 + lg * 8]);
        #pragma unroll
        for (int j = 0; j < 4; ++j)
            bfr[j] = *(f16x8*)(&Bs[(n0w + j * 16 + lm) * 40 + lg * 8]);
        #pragma unroll
        for (int i = 0; i < 4; ++i)
            #pragma unroll
            for (int j = 0; j < 4; ++j)
                acc[i][j] = __builtin_amdgcn_mfma_f32_16x16x32_f16(
                    af[i], bfr[j], acc[i][j], 0, 0, 0);
        __syncthreads();
    }

    if constexpr (OMODE == 1) {
        // fp16 tile -> LDS; n-major coalesced stores + fused scores
        __half (*Cs)[136] = (__half(*)[136])smem;
        #pragma unroll
        for (int i = 0; i < 4; ++i)
            #pragma unroll
            for (int r = 0; r < 4; ++r) {
                int lr = m0w + i * 16 + lg * 4 + r;
                #pragma unroll
                for (int j = 0; j < 4; ++j)
                    Cs[lr][n0w + j * 16 + lm] = __float2half(acc[i][j][r]);
            }
        __syncthreads();
        __half* C = (__half*)Cp;
        #pragma unroll
        for (int l = 0; l < 8; ++l) {
            int c = tid + l * 256;
            int rr = c >> 4, cc = c & 15;
            int gr = row0 + rr;
            if (gr < M)
                *(uint4*)(C + (size_t)gr * CDIM + col0 + cc * 8) = *(uint4*)(&Cs[rr][cc * 8]);
        }
        // fused scores: thread t -> (row t>>1, head-sel t&1); block covers 2 heads
        {
            int row = tid >> 1, hsel = tid & 1;
            int gr = row0 + row;
            if (gr < M) {
                int ghead = (col0 >> 6) + hsel;
                const float* w1 = a1w + ghead * 64;
                const float* w2 = a2w + ghead * 64;
                const uint* cp = (const uint*)&Cs[row][hsel * 64];
                float s1 = 0.f, s2 = 0.f;
                #pragma unroll
                for (int j = 0; j < 32; ++j) {
                    uint u = cp[j];
                    float2 f = __half22float2(*(__half2*)&u);
                    s1 += f.x * w1[2*j] + f.y * w1[2*j+1];
                    s2 += f.x * w2[2*j] + f.y * w2[2*j+1];
                }
                a1v[(size_t)gr * H + ghead] = s1 + a1b[ghead];
                a2v[(size_t)gr * H + ghead] = s2 + a2b[ghead];
            }
        }
    } else {
        // collator + fused classifier partials (R8). feat stays in registers.
        const float* Wc4 = a1w;     // Wcls [OUTC][CDIM] fp32
        float* pcls = a1v;          // [M][4][OUTC] partials
        const int slot = blockIdx.y * 2 + (wave >> 1);
        float wv[OUTC][4];
        #pragma unroll
        for (int o = 0; o < OUTC; ++o)
            #pragma unroll
            for (int j = 0; j < 4; ++j)
                wv[o][j] = Wc4[o * CDIM + col0 + n0w + j * 16 + lm];
        #pragma unroll
        for (int i = 0; i < 4; ++i)
            #pragma unroll
            for (int r = 0; r < 4; ++r) {
                int grow = row0 + m0w + i * 16 + lg * 4 + r;
                if (grow < M) {
                    float po[OUTC] = {0.f, 0.f, 0.f, 0.f};
                    #pragma unroll
                    for (int j = 0; j < 4; ++j) {
                        int gcol = col0 + n0w + j * 16 + lm;
                        float t = fmaxf(acc[i][j][r] + bias[gcol], 0.f);
                        #pragma unroll
                        for (int o = 0; o < OUTC; ++o)
                            po[o] = fmaf(t, wv[o][j], po[o]);
                    }
                    // reduce over the 16 lanes (lm) sharing this row
                    #pragma unroll
                    for (int m = 1; m < 16; m <<= 1)
                        #pragma unroll
                        for (int o = 0; o < OUTC; ++o)
                            po[o] += __shfl_xor(po[o], m);
                    if (lm < OUTC) {
                        float v = (lm == 0) ? po[0] : (lm == 1) ? po[1]
                                : (lm == 2) ? po[2] : po[3];
                        pcls[((size_t)grow * 4 + slot) * OUTC + lm] = v;
                    }
                }
            }
        (void)Cp;
    }
}

// ---------------------------------------------------------------------------
// Edge aggregation, R10: escore FUSED. Per edge, the 16-lane head-group
// computes its own score sv = exp(leaky(a1[n][head] + a2[d][head])) inline:
// a2v is a 1.6 MB L2-resident table (4 extra lines per batch next to the 8
// row-gathers already in flight); exp is ~1 extra VALU-transcendental per
// edge (VALUBusy was 53%). Removes: escore_k x2 dispatches, sExp 25.6 MB
// write + 25.6 MB read + colI re-read. Structure otherwise R6-proven:
// 1 wave per node, lane owns dims lane*4..+3, 8 gathers in flight.
// ---------------------------------------------------------------------------
__global__ __launch_bounds__(256) void agg_k(
    const __half* __restrict__ h,
    const float* __restrict__ a1v, const float* __restrict__ a2v,
    const int* __restrict__ rowStart, const int* __restrict__ colI,
    const float* __restrict__ bias, __half* __restrict__ outp, int relu, int Nn)
{
    int tid = threadIdx.x;
    int wave = tid >> 6, lane = tid & 63;
    int n = blockIdx.x * 4 + wave;
    if (n >= Nn) return;
    int head = lane >> 4;
    int s = rowStart[n], e = rowStart[n + 1];
    float ac0 = 0.f, ac1 = 0.f, ac2 = 0.f, ac3 = 0.f, den = 0.f;
    const __half* hl = h + lane * 4;
    const float a1n = a1v[(size_t)n * H + head];

    for (int p0 = s; p0 < e; p0 += 8) {
        int d[8]; float a2q[8]; ushort4 u[8];
        #pragma unroll
        for (int q = 0; q < 8; ++q) {
            int p = p0 + q;
            if (p < e) d[q] = colI[p];
        }
        #pragma unroll
        for (int q = 0; q < 8; ++q) {
            if (p0 + q < e) {
                u[q] = *(const ushort4*)(hl + (size_t)d[q] * CDIM);
                a2q[q] = a2v[(size_t)d[q] * H + head];
            }
        }
        #pragma unroll
        for (int q = 0; q < 8; ++q) {
            if (p0 + q < e) {
                float z = a1n + a2q[q];
                z = (z > 0.f) ? z : ALPHA * z;
                float svq = __expf(z);
                den += svq;
                ac0 = fmaf(svq, __half2float(__ushort_as_half(u[q].x)), ac0);
                ac1 = fmaf(svq, __half2float(__ushort_as_half(u[q].y)), ac1);
                ac2 = fmaf(svq, __half2float(__ushort_as_half(u[q].z)), ac2);
                ac3 = fmaf(svq, __half2float(__ushort_as_half(u[q].w)), ac3);
            }
        }
    }

    den = (den > 0.f) ? den : 1.f;
    const float4 b4 = *(const float4*)(bias + lane * 4);
    float r0 = ac0 / den + b4.x;
    float r1 = ac1 / den + b4.y;
    float r2 = ac2 / den + b4.z;
    float r3 = ac3 / den + b4.w;
    if (relu) {
        r0 = fmaxf(r0, 0.f); r1 = fmaxf(r1, 0.f);
        r2 = fmaxf(r2, 0.f); r3 = fmaxf(r3, 0.f);
    }
    ushort4 o;
    o.x = __half_as_ushort(__float2half(r0));
    o.y = __half_as_ushort(__float2half(r1));
    o.z = __half_as_ushort(__float2half(r2));
    o.w = __half_as_ushort(__float2half(r3));
    *(ushort4*)(outp + (size_t)n * CDIM + lane * 4) = o;
}

// ---------------------------------------------------------------------------
// Classifier finalize (R8): sum the 4 per-wave partials + bias; dtype per flag.
// ---------------------------------------------------------------------------
__global__ void cls2_k(const float* __restrict__ pcls, const float* __restrict__ bcls,
                       void* __restrict__ out, int Nn, const int* __restrict__ flagp)
{
    int n = blockIdx.x * 256 + threadIdx.x;
    if (n >= Nn) return;
    const float4 p0 = *(const float4*)(pcls + (size_t)n * 16);
    const float4 p1 = *(const float4*)(pcls + (size_t)n * 16 + 4);
    const float4 p2 = *(const float4*)(pcls + (size_t)n * 16 + 8);
    const float4 p3 = *(const float4*)(pcls + (size_t)n * 16 + 12);
    float r0 = p0.x + p1.x + p2.x + p3.x + bcls[0];
    float r1 = p0.y + p1.y + p2.y + p3.y + bcls[1];
    float r2 = p0.z + p1.z + p2.z + p3.z + bcls[2];
    float r3 = p0.w + p1.w + p2.w + p3.w + bcls[3];
    if (*flagp) {
        __hip_bfloat16* o = (__hip_bfloat16*)out + (size_t)n * OUTC;
        o[0] = __float2bfloat16(r0); o[1] = __float2bfloat16(r1);
        o[2] = __float2bfloat16(r2); o[3] = __float2bfloat16(r3);
    } else {
        float* o = (float*)out + (size_t)n * OUTC;
        o[0] = r0; o[1] = r1; o[2] = r2; o[3] = r3;
    }
}

// ---------------------------------------------------------------------------
extern "C" void kernel_launch(void* const* d_in, const int* in_sizes, int n_in,
                              void* d_out, int out_size, void* d_ws, size_t ws_size,
                              hipStream_t stream)
{
    const void* x  = d_in[0];
    const int*  ei = (const int*)d_in[1];

    const int Nn = in_sizes[0] / CDIM;   // 100000
    const int Ee = in_sizes[1] / 2;      // 1600000
    const int* srcI = ei;
    const int* dstI = ei + Ee;

    char* wsp = (char*)d_ws;
    size_t off = 0;
    auto alloc = [&](size_t bytes) -> void* {
        void* p = wsp + off;
        off += (bytes + 255) & ~(size_t)255;
        return p;
    };
    __half* hA   = (__half*)alloc((size_t)Nn * CDIM * 2);  // 51.2 MB
    __half* hB   = (__half*)alloc((size_t)Nn * CDIM * 2);  // 51.2 MB
    float*  a1v       = (float*)alloc((size_t)Nn * H * 4);
    float*  a2v       = (float*)alloc((size_t)Nn * H * 4);
    float*  pcls      = (float*)alloc((size_t)Nn * 4 * OUTC * 4); // 6.4 MB
    int*    rowStart  = (int*)alloc((size_t)(Nn + 1) * 4);
    int*    colI      = (int*)alloc((size_t)Ee * 4);       // 6.4 MB
    uint32_t* pairs   = (uint32_t*)alloc((size_t)Ee * 4);  // 6.4 MB packed
    int*    bucketCnt   = (int*)alloc(MAXB * 4);
    int*    bucketCur   = (int*)alloc(MAXB * 4);
    int*    bucketStart = (int*)alloc((MAXB + 1) * 4);
    int*    flag      = (int*)alloc(256);
    float*  wconv     = (float*)alloc((size_t)200000 * 4);
    __half* wh        = (__half*)alloc((size_t)200000 * 2);
    (void)ws_size; (void)n_in; (void)out_size;

    // dtype detect + weight conversion (proven machinery)
    detect_k<<<1, 256, 0, stream>>>((const uint32_t*)x, flag);
    WPtrs wp;
    int woff = 0;
    for (int i = 0; i < NW; ++i) {
        wp.p[i] = d_in[2 + i];
        wp.sz[i] = in_sizes[2 + i];
        wp.off[i] = woff;
        woff += in_sizes[2 + i];
    }
    {
        dim3 cgrid(256, NW);
        convert_k<<<cgrid, 256, 0, stream>>>(wp, wconv, wh, flag);
    }
    const float*  a11wf = wconv + wp.off[1];
    const float*  a11bf = wconv + wp.off[2];
    const float*  a12wf = wconv + wp.off[3];
    const float*  a12bf = wconv + wp.off[4];
    const float*  b1f   = wconv + wp.off[5];
    const float*  a21wf = wconv + wp.off[7];
    const float*  a21bf = wconv + wp.off[8];
    const float*  a22wf = wconv + wp.off[9];
    const float*  a22bf = wconv + wp.off[10];
    const float*  b2f   = wconv + wp.off[11];
    const float*  bcf   = wconv + wp.off[13];
    const float*  Wclsf = wconv + wp.off[14];
    const float*  bclsf = wconv + wp.off[15];
    const __half* W1h   = wh + wp.off[0];
    const __half* W2h   = wh + wp.off[6];
    const __half* Wch   = wh + wp.off[12];

    const int NB = (Nn + 255) / 256;          // node blocks (391)
    const int NBUCK = (Nn + 255) >> 8;        // buckets (391, <= MAXB)
    const int TB = (Ee + TILE1 - 1) / TILE1;  // edge tiles (391)

    // CSR build (R9 binning pipeline)
    hipMemsetAsync(bucketCnt, 0, MAXB * 4, stream);
    bhist_k<<<TB, 512, 0, stream>>>(srcI, bucketCnt, Ee, NBUCK);
    bscan_k<<<1, 512, 0, stream>>>(bucketCnt, bucketCur, bucketStart, rowStart,
                                   NBUCK, Nn, Ee);
    pass1_k<<<TB, 512, 0, stream>>>(srcI, dstI, bucketCur, pairs, Ee, NBUCK);
    pass2_k<<<NBUCK, 256, 0, stream>>>(pairs, bucketStart, rowStart, colI, Nn);

    dim3 ggrid((Nn + 127) / 128, CDIM / 128);   // (782, 2)
    const int AB = (Nn + 3) / 4;                // 4 nodes (waves) per block

    // Layer 1: gemm(raw x) -> hA (+ fused scores); agg (fused escore) -> hB
    gemm_k<0, 1><<<ggrid, 256, 0, stream>>>(x, W1h, nullptr, hA, Nn, flag,
                                            a11wf, a11bf, a12wf, a12bf, a1v, a2v);
    agg_k<<<AB, 256, 0, stream>>>(hA, a1v, a2v, rowStart, colI, b1f, hB, 1, Nn);

    // Layer 2: gemm(hB) -> hA (+ fused scores); agg (fused escore) -> hB
    gemm_k<1, 1><<<ggrid, 256, 0, stream>>>(hB, W2h, nullptr, hA, Nn, flag,
                                            a21wf, a21bf, a22wf, a22bf, a1v, a2v);
    agg_k<<<AB, 256, 0, stream>>>(hA, a1v, a2v, rowStart, colI, b2f, hB, 0, Nn);

    // Collator + fused classifier partials; then finalize
    gemm_k<1, 0><<<ggrid, 256, 0, stream>>>(hB, Wch, bcf, nullptr, Nn, flag,
                                            Wclsf, nullptr, nullptr, nullptr,
                                            pcls, nullptr);
    cls2_k<<<NB, 256, 0, stream>>>(pcls, bclsf, d_out, Nn, flag);
}

// Round 6
// 641.614 us; speedup vs baseline: 1.5120x; 1.0153x over previous
//
#include <hip/hip_runtime.h>
#include <hip/hip_bf16.h>
#include <hip/hip_fp16.h>
#include <stdint.h>

#define H 4
#define HID 64
#define CDIM 256   /* = H*HID = IN = FC */
#define OUTC 4
#define ALPHA 0.2f
#define NW 16      /* number of float weight inputs (d_in[2..17]) */
#define MAXB 512   /* max buckets; NBUCK = ceil(Nn/256) <= 512 for Nn <= 131072 */
#define TILE1 4096 /* edges per pass1 tile (8 per thread x 512 threads) */

typedef __attribute__((ext_vector_type(8))) _Float16 f16x8;
typedef __attribute__((ext_vector_type(4))) float f32x4;

// ---------------------------------------------------------------------------
// dtype detection (R2/R4/R5-proven; real answer on this harness: fp32, flag=0)
// ---------------------------------------------------------------------------
__global__ void detect_k(const uint32_t* __restrict__ xw, int* __restrict__ flag) {
    __shared__ int sd[256];
    int t = threadIdx.x;
    int hits = 0;
    for (int i = 0; i < 16; ++i) {
        uint32_t w = xw[t * 16 + i];
        uint32_t ex = (w >> 7) & 0xffu;
        if (ex >= 100u && ex <= 145u) hits++;
    }
    sd[t] = hits;
    __syncthreads();
    for (int s = 128; s > 0; s >>= 1) {
        if (t < s) sd[t] += sd[t + s];
        __syncthreads();
    }
    if (t == 0) *flag = (sd[0] > 3000) ? 1 : 0;
}

// ---------------------------------------------------------------------------
// Convert all 16 weight tensors to fp32 AND fp16 in ws (branch on flag).
// ---------------------------------------------------------------------------
struct WPtrs {
    const void* p[NW];
    int sz[NW];
    int off[NW];
};

__global__ void convert_k(WPtrs ptrs, float* __restrict__ outf, __half* __restrict__ outh,
                          const int* __restrict__ flag) {
    int which = blockIdx.y;
    int n = ptrs.sz[which];
    int i = blockIdx.x * 256 + threadIdx.x;
    if (i >= n) return;
    float v;
    if (*flag) v = __bfloat162float(((const __hip_bfloat16*)ptrs.p[which])[i]);
    else       v = ((const float*)ptrs.p[which])[i];
    outf[ptrs.off[which] + i] = v;
    outh[ptrs.off[which] + i] = __float2half(v);
}

// ---------------------------------------------------------------------------
// CSR build, R9 binning pipeline (R4-proven: dense accesses, no global
// random atomics; replaced the 125us scatter).
// ---------------------------------------------------------------------------
__global__ __launch_bounds__(512) void bhist_k(const int* __restrict__ srcI,
                                               int* __restrict__ bucketCnt,
                                               int Ee, int nbuck)
{
    __shared__ int bc[MAXB];
    int t = threadIdx.x;
    bc[t] = 0;
    __syncthreads();
    int base = blockIdx.x * TILE1;
    #pragma unroll
    for (int q = 0; q < 8; ++q) {
        int i = base + q * 512 + t;
        if (i < Ee) atomicAdd(&bc[srcI[i] >> 8], 1);
    }
    __syncthreads();
    if (t < nbuck && bc[t] > 0) atomicAdd(&bucketCnt[t], bc[t]);
}

__global__ __launch_bounds__(512) void bscan_k(
    const int* __restrict__ bucketCnt, int* __restrict__ bucketCur,
    int* __restrict__ bucketStart, int* __restrict__ rowStart,
    int nbuck, int Nn, int Ee)
{
    __shared__ int sd[MAXB];
    int t = threadIdx.x;
    int v = (t < nbuck) ? bucketCnt[t] : 0;
    sd[t] = v;
    __syncthreads();
    for (int off = 1; off < MAXB; off <<= 1) {
        int add = (t >= off) ? sd[t - off] : 0;
        __syncthreads();
        sd[t] += add;
        __syncthreads();
    }
    if (t < nbuck) {
        int excl = sd[t] - v;
        bucketCur[t] = excl;
        bucketStart[t] = excl;
    }
    if (t == 0) { bucketStart[nbuck] = Ee; rowStart[Nn] = Ee; }
}

__global__ __launch_bounds__(512) void pass1_k(
    const int* __restrict__ srcI, const int* __restrict__ dstI,
    int* __restrict__ bucketCur, uint32_t* __restrict__ pairs,
    int Ee, int nbuck)
{
    __shared__ int cntL[MAXB], scanL[MAXB], exclL[MAXB], curL[MAXB], gbaseL[MAXB];
    __shared__ uint32_t sortedV[TILE1];
    __shared__ uint16_t sortedB[TILE1];
    const int t = threadIdx.x;
    const int base = blockIdx.x * TILE1;
    cntL[t] = 0;
    __syncthreads();
    uint32_t vq[8]; int bq[8];
    #pragma unroll
    for (int q = 0; q < 8; ++q) {
        int i = base + q * 512 + t;
        if (i < Ee) {
            int s = srcI[i], d = dstI[i];
            bq[q] = s >> 8;
            vq[q] = ((uint32_t)d << 8) | (uint32_t)(s & 255);
            atomicAdd(&cntL[bq[q]], 1);
        } else bq[q] = -1;
    }
    __syncthreads();
    scanL[t] = cntL[t];
    __syncthreads();
    for (int off = 1; off < MAXB; off <<= 1) {
        int add = (t >= off) ? scanL[t - off] : 0;
        __syncthreads();
        scanL[t] += add;
        __syncthreads();
    }
    int excl = scanL[t] - cntL[t];
    exclL[t] = excl;
    curL[t] = excl;
    if (t < nbuck && cntL[t] > 0)
        gbaseL[t] = atomicAdd(&bucketCur[t], cntL[t]);
    __syncthreads();
    #pragma unroll
    for (int q = 0; q < 8; ++q) {
        if (bq[q] >= 0) {
            int pos = atomicAdd(&curL[bq[q]], 1);
            sortedV[pos] = vq[q];
            sortedB[pos] = (uint16_t)bq[q];
        }
    }
    __syncthreads();
    int tcount = min(TILE1, Ee - base);
    for (int j = t; j < tcount; j += 512) {
        int b = sortedB[j];
        pairs[gbaseL[b] + (j - exclL[b])] = sortedV[j];
    }
}

__global__ __launch_bounds__(256) void pass2_k(
    const uint32_t* __restrict__ pairs, const int* __restrict__ bucketStart,
    int* __restrict__ rowStart, int* __restrict__ colI, int Nn)
{
    __shared__ int ncnt[256], sd[256], lcur[256];
    int b = blockIdx.x, t = threadIdx.x;
    int n0 = b << 8;
    int s = bucketStart[b], e = bucketStart[b + 1];
    ncnt[t] = 0;
    __syncthreads();
    for (int p = s + t; p < e; p += 256)
        atomicAdd(&ncnt[pairs[p] & 255], 1);
    __syncthreads();
    int v = ncnt[t];
    sd[t] = v;
    __syncthreads();
    for (int off = 1; off < 256; off <<= 1) {
        int add = (t >= off) ? sd[t - off] : 0;
        __syncthreads();
        sd[t] += add;
        __syncthreads();
    }
    int start = s + sd[t] - v;
    lcur[t] = start;
    if (n0 + t < Nn) rowStart[n0 + t] = start;
    __syncthreads();
    for (int p = s + t; p < e; p += 256) {
        uint32_t pv = pairs[p];
        int q = atomicAdd(&lcur[pv & 255], 1);
        colI[q] = (int)(pv >> 8);
    }
}

// ---------------------------------------------------------------------------
// f16 MFMA GEMM, 128x128 tile / 4 waves, BK=32, mfma_f32_16x16x32_f16.
// AMODE 0: A = raw x (fp32 or bf16 per *flag), convert to fp16 in staging.
// AMODE 1: A = fp16 n-major [M][256].
// OMODE 0: collator + FUSED classifier (R8): per-wave 64-col partial logits,
//          slot = blockIdx.y*2 + (wave>>1) (4 distinct slots per row).
// OMODE 1: fp16 n-major out [M][256] (pre-relu, no bias) + fused attention
//          scores: a1v[n][head] fp32, a2v[n][head] fp16 (R11: halved table
//          so agg's random a2 gathers stay L2-resident under h-row thrash).
// ---------------------------------------------------------------------------
template <int AMODE, int OMODE>
__global__ __launch_bounds__(256) void gemm_k(
    const void* __restrict__ Ap, const __half* __restrict__ B,
    const float* __restrict__ bias, void* __restrict__ Cp, int M,
    const int* __restrict__ flagp,
    const float* __restrict__ a1w, const float* __restrict__ a1b,
    const float* __restrict__ a2w, const float* __restrict__ a2b,
    float* __restrict__ a1v, __half* __restrict__ a2v)
{
    __shared__ __align__(16) char smem[128 * 136 * 2];   // 34.8 KB
    short* As = (short*)smem;              // 128*40 shorts
    short* Bs = (short*)(smem + 10240);
    const int tid  = threadIdx.x;
    const int row0 = blockIdx.x * 128;
    const int col0 = blockIdx.y * 128;
    const int wave = tid >> 6, lane = tid & 63;
    const int m0w = (wave & 1) * 64;
    const int n0w = (wave >> 1) * 64;
    const int lm = lane & 15, lg = lane >> 4;
    const int isbf = (AMODE == 0) ? *flagp : 0;

    f32x4 acc[4][4] = {};

    for (int k0 = 0; k0 < CDIM; k0 += 32) {
        #pragma unroll
        for (int l = 0; l < 2; ++l) {
            int c = tid + l * 256;
            int m = c >> 2, kc = c & 3;
            int gr = row0 + m;
            uint4 q = make_uint4(0u, 0u, 0u, 0u);
            if constexpr (AMODE == 1) {
                const __half* A = (const __half*)Ap;
                if (gr < M) q = *(const uint4*)(A + (size_t)gr * CDIM + k0 + kc * 8);
            } else {
                if (gr < M) {
                    __half hv[8];
                    if (isbf) {
                        const uint4 qb = *(const uint4*)((const __hip_bfloat16*)Ap
                                           + (size_t)gr * CDIM + k0 + kc * 8);
                        const uint32_t* w = (const uint32_t*)&qb;
                        #pragma unroll
                        for (int p = 0; p < 4; ++p) {
                            hv[2*p]   = __float2half(__uint_as_float((w[p] & 0xffffu) << 16));
                            hv[2*p+1] = __float2half(__uint_as_float(w[p] & 0xffff0000u));
                        }
                    } else {
                        const float* A = (const float*)Ap + (size_t)gr * CDIM + k0 + kc * 8;
                        const float4 f0 = *(const float4*)A;
                        const float4 f1 = *(const float4*)(A + 4);
                        hv[0]=__float2half(f0.x); hv[1]=__float2half(f0.y);
                        hv[2]=__float2half(f0.z); hv[3]=__float2half(f0.w);
                        hv[4]=__float2half(f1.x); hv[5]=__float2half(f1.y);
                        hv[6]=__float2half(f1.z); hv[7]=__float2half(f1.w);
                    }
                    q = *(uint4*)hv;
                }
            }
            *(uint4*)(&As[m * 40 + kc * 8]) = q;
        }
        #pragma unroll
        for (int l = 0; l < 2; ++l) {
            int c = tid + l * 256;
            int nn = c >> 2, kc = c & 3;
            uint4 q = *(const uint4*)(B + (size_t)(col0 + nn) * CDIM + k0 + kc * 8);
            *(uint4*)(&Bs[nn * 40 + kc * 8]) = q;
        }
        __syncthreads();
        f16x8 af[4], bfr[4];
        #pragma unroll
        for (int i = 0; i < 4; ++i)
            af[i] = *(f16x8*)(&As[(m0w + i * 16 + lm) * 40 + lg * 8]);
        #pragma unroll
        for (int j = 0; j < 4; ++j)
            bfr[j] = *(f16x8*)(&Bs[(n0w + j * 16 + lm) * 40 + lg * 8]);
        #pragma unroll
        for (int i = 0; i < 4; ++i)
            #pragma unroll
            for (int j = 0; j < 4; ++j)
                acc[i][j] = __builtin_amdgcn_mfma_f32_16x16x32_f16(
                    af[i], bfr[j], acc[i][j], 0, 0, 0);
        __syncthreads();
    }

    if constexpr (OMODE == 1) {
        // fp16 tile -> LDS; n-major coalesced stores + fused scores
        __half (*Cs)[136] = (__half(*)[136])smem;
        #pragma unroll
        for (int i = 0; i < 4; ++i)
            #pragma unroll
            for (int r = 0; r < 4; ++r) {
                int lr = m0w + i * 16 + lg * 4 + r;
                #pragma unroll
                for (int j = 0; j < 4; ++j)
                    Cs[lr][n0w + j * 16 + lm] = __float2half(acc[i][j][r]);
            }
        __syncthreads();
        __half* C = (__half*)Cp;
        #pragma unroll
        for (int l = 0; l < 8; ++l) {
            int c = tid + l * 256;
            int rr = c >> 4, cc = c & 15;
            int gr = row0 + rr;
            if (gr < M)
                *(uint4*)(C + (size_t)gr * CDIM + col0 + cc * 8) = *(uint4*)(&Cs[rr][cc * 8]);
        }
        // fused scores: thread t -> (row t>>1, head-sel t&1); block covers 2 heads
        {
            int row = tid >> 1, hsel = tid & 1;
            int gr = row0 + row;
            if (gr < M) {
                int ghead = (col0 >> 6) + hsel;
                const float* w1 = a1w + ghead * 64;
                const float* w2 = a2w + ghead * 64;
                const uint* cp = (const uint*)&Cs[row][hsel * 64];
                float s1 = 0.f, s2 = 0.f;
                #pragma unroll
                for (int j = 0; j < 32; ++j) {
                    uint u = cp[j];
                    float2 f = __half22float2(*(__half2*)&u);
                    s1 += f.x * w1[2*j] + f.y * w1[2*j+1];
                    s2 += f.x * w2[2*j] + f.y * w2[2*j+1];
                }
                a1v[(size_t)gr * H + ghead] = s1 + a1b[ghead];
                a2v[(size_t)gr * H + ghead] = __float2half(s2 + a2b[ghead]);
            }
        }
    } else {
        // collator + fused classifier partials (R8). feat stays in registers.
        const float* Wc4 = a1w;     // Wcls [OUTC][CDIM] fp32
        float* pcls = a1v;          // [M][4][OUTC] partials
        const int slot = blockIdx.y * 2 + (wave >> 1);
        float wv[OUTC][4];
        #pragma unroll
        for (int o = 0; o < OUTC; ++o)
            #pragma unroll
            for (int j = 0; j < 4; ++j)
                wv[o][j] = Wc4[o * CDIM + col0 + n0w + j * 16 + lm];
        #pragma unroll
        for (int i = 0; i < 4; ++i)
            #pragma unroll
            for (int r = 0; r < 4; ++r) {
                int grow = row0 + m0w + i * 16 + lg * 4 + r;
                if (grow < M) {
                    float po[OUTC] = {0.f, 0.f, 0.f, 0.f};
                    #pragma unroll
                    for (int j = 0; j < 4; ++j) {
                        int gcol = col0 + n0w + j * 16 + lm;
                        float t = fmaxf(acc[i][j][r] + bias[gcol], 0.f);
                        #pragma unroll
                        for (int o = 0; o < OUTC; ++o)
                            po[o] = fmaf(t, wv[o][j], po[o]);
                    }
                    // reduce over the 16 lanes (lm) sharing this row
                    #pragma unroll
                    for (int m = 1; m < 16; m <<= 1)
                        #pragma unroll
                        for (int o = 0; o < OUTC; ++o)
                            po[o] += __shfl_xor(po[o], m);
                    if (lm < OUTC) {
                        float v = (lm == 0) ? po[0] : (lm == 1) ? po[1]
                                : (lm == 2) ? po[2] : po[3];
                        pcls[((size_t)grow * 4 + slot) * OUTC + lm] = v;
                    }
                }
            }
        (void)Cp;
    }
}

// ---------------------------------------------------------------------------
// Edge aggregation, R11: fused escore kept, but
//  (a) BRANCHLESS full-depth batch: clamped index p0+(q<cnt?q:0) (always
//      in-bounds; tail duplicates edge 0 with weight masked to 0). R5's
//      per-q guards let the compiler serialize the batch (VGPR_Count=28 <
//      the 32+ needed for d[8]+a2q[8]+u[8] in flight). Straight-line loads
//      force all 16 loads issued before the first waitcnt.
//  (b) a2 table in fp16 (0.8 MB): halves the footprint that thrashes
//      against the h-row stream in per-XCD L2 (R5: +50 MB HBM from a2
//      misses). z quantization ~2e-3 << 7.4e-3 threshold.
// Structure otherwise R6-proven: 1 wave/node, lane owns dims lane*4..+3,
// 8 row-gathers in flight.
// ---------------------------------------------------------------------------
__global__ __launch_bounds__(256) void agg_k(
    const __half* __restrict__ h,
    const float* __restrict__ a1v, const __half* __restrict__ a2v,
    const int* __restrict__ rowStart, const int* __restrict__ colI,
    const float* __restrict__ bias, __half* __restrict__ outp, int relu, int Nn)
{
    int tid = threadIdx.x;
    int wave = tid >> 6, lane = tid & 63;
    int n = blockIdx.x * 4 + wave;
    if (n >= Nn) return;
    int head = lane >> 4;
    int s = rowStart[n], e = rowStart[n + 1];
    float ac0 = 0.f, ac1 = 0.f, ac2 = 0.f, ac3 = 0.f, den = 0.f;
    const __half* hl = h + lane * 4;
    const float a1n = a1v[(size_t)n * H + head];

    for (int p0 = s; p0 < e; p0 += 8) {
        const int cnt = e - p0;            // wave-uniform; >= 1
        int d[8]; float a2q[8]; ushort4 u[8];
        #pragma unroll
        for (int q = 0; q < 8; ++q) {
            int p = p0 + ((q < cnt) ? q : 0);   // clamped: always < e
            d[q] = colI[p];
        }
        #pragma unroll
        for (int q = 0; q < 8; ++q) {
            u[q] = *(const ushort4*)(hl + (size_t)d[q] * CDIM);
            a2q[q] = __half2float(a2v[(size_t)d[q] * H + head]);
        }
        #pragma unroll
        for (int q = 0; q < 8; ++q) {
            float z = a1n + a2q[q];
            z = (z > 0.f) ? z : ALPHA * z;
            float svq = (q < cnt) ? __expf(z) : 0.f;
            den += svq;
            ac0 = fmaf(svq, __half2float(__ushort_as_half(u[q].x)), ac0);
            ac1 = fmaf(svq, __half2float(__ushort_as_half(u[q].y)), ac1);
            ac2 = fmaf(svq, __half2float(__ushort_as_half(u[q].z)), ac2);
            ac3 = fmaf(svq, __half2float(__ushort_as_half(u[q].w)), ac3);
        }
    }

    den = (den > 0.f) ? den : 1.f;
    const float4 b4 = *(const float4*)(bias + lane * 4);
    float r0 = ac0 / den + b4.x;
    float r1 = ac1 / den + b4.y;
    float r2 = ac2 / den + b4.z;
    float r3 = ac3 / den + b4.w;
    if (relu) {
        r0 = fmaxf(r0, 0.f); r1 = fmaxf(r1, 0.f);
        r2 = fmaxf(r2, 0.f); r3 = fmaxf(r3, 0.f);
    }
    ushort4 o;
    o.x = __half_as_ushort(__float2half(r0));
    o.y = __half_as_ushort(__float2half(r1));
    o.z = __half_as_ushort(__float2half(r2));
    o.w = __half_as_ushort(__float2half(r3));
    *(ushort4*)(outp + (size_t)n * CDIM + lane * 4) = o;
}

// ---------------------------------------------------------------------------
// Classifier finalize (R8): sum the 4 per-wave partials + bias; dtype per flag.
// ---------------------------------------------------------------------------
__global__ void cls2_k(const float* __restrict__ pcls, const float* __restrict__ bcls,
                       void* __restrict__ out, int Nn, const int* __restrict__ flagp)
{
    int n = blockIdx.x * 256 + threadIdx.x;
    if (n >= Nn) return;
    const float4 p0 = *(const float4*)(pcls + (size_t)n * 16);
    const float4 p1 = *(const float4*)(pcls + (size_t)n * 16 + 4);
    const float4 p2 = *(const float4*)(pcls + (size_t)n * 16 + 8);
    const float4 p3 = *(const float4*)(pcls + (size_t)n * 16 + 12);
    float r0 = p0.x + p1.x + p2.x + p3.x + bcls[0];
    float r1 = p0.y + p1.y + p2.y + p3.y + bcls[1];
    float r2 = p0.z + p1.z + p2.z + p3.z + bcls[2];
    float r3 = p0.w + p1.w + p2.w + p3.w + bcls[3];
    if (*flagp) {
        __hip_bfloat16* o = (__hip_bfloat16*)out + (size_t)n * OUTC;
        o[0] = __float2bfloat16(r0); o[1] = __float2bfloat16(r1);
        o[2] = __float2bfloat16(r2); o[3] = __float2bfloat16(r3);
    } else {
        float* o = (float*)out + (size_t)n * OUTC;
        o[0] = r0; o[1] = r1; o[2] = r2; o[3] = r3;
    }
}

// ---------------------------------------------------------------------------
extern "C" void kernel_launch(void* const* d_in, const int* in_sizes, int n_in,
                              void* d_out, int out_size, void* d_ws, size_t ws_size,
                              hipStream_t stream)
{
    const void* x  = d_in[0];
    const int*  ei = (const int*)d_in[1];

    const int Nn = in_sizes[0] / CDIM;   // 100000
    const int Ee = in_sizes[1] / 2;      // 1600000
    const int* srcI = ei;
    const int* dstI = ei + Ee;

    char* wsp = (char*)d_ws;
    size_t off = 0;
    auto alloc = [&](size_t bytes) -> void* {
        void* p = wsp + off;
        off += (bytes + 255) & ~(size_t)255;
        return p;
    };
    __half* hA   = (__half*)alloc((size_t)Nn * CDIM * 2);  // 51.2 MB
    __half* hB   = (__half*)alloc((size_t)Nn * CDIM * 2);  // 51.2 MB
    float*  a1v       = (float*)alloc((size_t)Nn * H * 4);
    __half* a2h       = (__half*)alloc((size_t)Nn * H * 2); // 0.8 MB fp16
    float*  pcls      = (float*)alloc((size_t)Nn * 4 * OUTC * 4); // 6.4 MB
    int*    rowStart  = (int*)alloc((size_t)(Nn + 1) * 4);
    int*    colI      = (int*)alloc((size_t)Ee * 4);       // 6.4 MB
    uint32_t* pairs   = (uint32_t*)alloc((size_t)Ee * 4);  // 6.4 MB packed
    int*    bucketCnt   = (int*)alloc(MAXB * 4);
    int*    bucketCur   = (int*)alloc(MAXB * 4);
    int*    bucketStart = (int*)alloc((MAXB + 1) * 4);
    int*    flag      = (int*)alloc(256);
    float*  wconv     = (float*)alloc((size_t)200000 * 4);
    __half* wh        = (__half*)alloc((size_t)200000 * 2);
    (void)ws_size; (void)n_in; (void)out_size;

    // dtype detect + weight conversion (proven machinery)
    detect_k<<<1, 256, 0, stream>>>((const uint32_t*)x, flag);
    WPtrs wp;
    int woff = 0;
    for (int i = 0; i < NW; ++i) {
        wp.p[i] = d_in[2 + i];
        wp.sz[i] = in_sizes[2 + i];
        wp.off[i] = woff;
        woff += in_sizes[2 + i];
    }
    {
        dim3 cgrid(256, NW);
        convert_k<<<cgrid, 256, 0, stream>>>(wp, wconv, wh, flag);
    }
    const float*  a11wf = wconv + wp.off[1];
    const float*  a11bf = wconv + wp.off[2];
    const float*  a12wf = wconv + wp.off[3];
    const float*  a12bf = wconv + wp.off[4];
    const float*  b1f   = wconv + wp.off[5];
    const float*  a21wf = wconv + wp.off[7];
    const float*  a21bf = wconv + wp.off[8];
    const float*  a22wf = wconv + wp.off[9];
    const float*  a22bf = wconv + wp.off[10];
    const float*  b2f   = wconv + wp.off[11];
    const float*  bcf   = wconv + wp.off[13];
    const float*  Wclsf = wconv + wp.off[14];
    const float*  bclsf = wconv + wp.off[15];
    const __half* W1h   = wh + wp.off[0];
    const __half* W2h   = wh + wp.off[6];
    const __half* Wch   = wh + wp.off[12];

    const int NB = (Nn + 255) / 256;          // node blocks (391)
    const int NBUCK = (Nn + 255) >> 8;        // buckets (391, <= MAXB)
    const int TB = (Ee + TILE1 - 1) / TILE1;  // edge tiles (391)

    // CSR build (R9 binning pipeline)
    hipMemsetAsync(bucketCnt, 0, MAXB * 4, stream);
    bhist_k<<<TB, 512, 0, stream>>>(srcI, bucketCnt, Ee, NBUCK);
    bscan_k<<<1, 512, 0, stream>>>(bucketCnt, bucketCur, bucketStart, rowStart,
                                   NBUCK, Nn, Ee);
    pass1_k<<<TB, 512, 0, stream>>>(srcI, dstI, bucketCur, pairs, Ee, NBUCK);
    pass2_k<<<NBUCK, 256, 0, stream>>>(pairs, bucketStart, rowStart, colI, Nn);

    dim3 ggrid((Nn + 127) / 128, CDIM / 128);   // (782, 2)
    const int AB = (Nn + 3) / 4;                // 4 nodes (waves) per block

    // Layer 1: gemm(raw x) -> hA (+ fused scores); agg (fused escore) -> hB
    gemm_k<0, 1><<<ggrid, 256, 0, stream>>>(x, W1h, nullptr, hA, Nn, flag,
                                            a11wf, a11bf, a12wf, a12bf, a1v, a2h);
    agg_k<<<AB, 256, 0, stream>>>(hA, a1v, a2h, rowStart, colI, b1f, hB, 1, Nn);

    // Layer 2: gemm(hB) -> hA (+ fused scores); agg (fused escore) -> hB
    gemm_k<1, 1><<<ggrid, 256, 0, stream>>>(hB, W2h, nullptr, hA, Nn, flag,
                                            a21wf, a21bf, a22wf, a22bf, a1v, a2h);
    agg_k<<<AB, 256, 0, stream>>>(hA, a1v, a2h, rowStart, colI, b2f, hB, 0, Nn);

    // Collator + fused classifier partials; then finalize
    gemm_k<1, 0><<<ggrid, 256, 0, stream>>>(hB, Wch, bcf, nullptr, Nn, flag,
                                            Wclsf, nullptr, nullptr, nullptr,
                                            pcls, nullptr);
    cls2_k<<<NB, 256, 0, stream>>>(pcls, bclsf, d_out, Nn, flag);
}

// Round 7
// 622.135 us; speedup vs baseline: 1.5594x; 1.0313x over previous
//
#include <hip/hip_runtime.h>
#include <hip/hip_bf16.h>
#include <hip/hip_fp16.h>
#include <stdint.h>

#define H 4
#define HID 64
#define CDIM 256   /* = H*HID = IN = FC */
#define OUTC 4
#define ALPHA 0.2f
#define NW 16      /* number of float weight inputs (d_in[2..17]) */
#define MAXB 512   /* max buckets; NBUCK = ceil(Nn/256) <= 512 for Nn <= 131072 */
#define TILE1 4096 /* edges per pass1 tile (8 per thread x 512 threads) */

typedef __attribute__((ext_vector_type(8))) _Float16 f16x8;
typedef __attribute__((ext_vector_type(4))) float f32x4;

#define GLOBAL_AS(p) ((const __attribute__((address_space(1))) void*)(p))
#define LDS_AS(p)    ((__attribute__((address_space(3))) void*)(p))

// ---------------------------------------------------------------------------
// dtype detection (R2/R4/R5-proven; real answer on this harness: fp32, flag=0)
// ---------------------------------------------------------------------------
__global__ void detect_k(const uint32_t* __restrict__ xw, int* __restrict__ flag) {
    __shared__ int sd[256];
    int t = threadIdx.x;
    int hits = 0;
    for (int i = 0; i < 16; ++i) {
        uint32_t w = xw[t * 16 + i];
        uint32_t ex = (w >> 7) & 0xffu;
        if (ex >= 100u && ex <= 145u) hits++;
    }
    sd[t] = hits;
    __syncthreads();
    for (int s = 128; s > 0; s >>= 1) {
        if (t < s) sd[t] += sd[t + s];
        __syncthreads();
    }
    if (t == 0) *flag = (sd[0] > 3000) ? 1 : 0;
}

// ---------------------------------------------------------------------------
// Convert all 16 weight tensors to fp32 AND fp16 in ws (branch on flag).
// ---------------------------------------------------------------------------
struct WPtrs {
    const void* p[NW];
    int sz[NW];
    int off[NW];
};

__global__ void convert_k(WPtrs ptrs, float* __restrict__ outf, __half* __restrict__ outh,
                          const int* __restrict__ flag) {
    int which = blockIdx.y;
    int n = ptrs.sz[which];
    int i = blockIdx.x * 256 + threadIdx.x;
    if (i >= n) return;
    float v;
    if (*flag) v = __bfloat162float(((const __hip_bfloat16*)ptrs.p[which])[i]);
    else       v = ((const float*)ptrs.p[which])[i];
    outf[ptrs.off[which] + i] = v;
    outh[ptrs.off[which] + i] = __float2half(v);
}

// ---------------------------------------------------------------------------
// CSR build, R9 binning pipeline (R4-proven: dense accesses, no global
// random atomics; replaced the 125us scatter).
// ---------------------------------------------------------------------------
__global__ __launch_bounds__(512) void bhist_k(const int* __restrict__ srcI,
                                               int* __restrict__ bucketCnt,
                                               int Ee, int nbuck)
{
    __shared__ int bc[MAXB];
    int t = threadIdx.x;
    bc[t] = 0;
    __syncthreads();
    int base = blockIdx.x * TILE1;
    #pragma unroll
    for (int q = 0; q < 8; ++q) {
        int i = base + q * 512 + t;
        if (i < Ee) atomicAdd(&bc[srcI[i] >> 8], 1);
    }
    __syncthreads();
    if (t < nbuck && bc[t] > 0) atomicAdd(&bucketCnt[t], bc[t]);
}

__global__ __launch_bounds__(512) void bscan_k(
    const int* __restrict__ bucketCnt, int* __restrict__ bucketCur,
    int* __restrict__ bucketStart, int* __restrict__ rowStart,
    int nbuck, int Nn, int Ee)
{
    __shared__ int sd[MAXB];
    int t = threadIdx.x;
    int v = (t < nbuck) ? bucketCnt[t] : 0;
    sd[t] = v;
    __syncthreads();
    for (int off = 1; off < MAXB; off <<= 1) {
        int add = (t >= off) ? sd[t - off] : 0;
        __syncthreads();
        sd[t] += add;
        __syncthreads();
    }
    if (t < nbuck) {
        int excl = sd[t] - v;
        bucketCur[t] = excl;
        bucketStart[t] = excl;
    }
    if (t == 0) { bucketStart[nbuck] = Ee; rowStart[Nn] = Ee; }
}

__global__ __launch_bounds__(512) void pass1_k(
    const int* __restrict__ srcI, const int* __restrict__ dstI,
    int* __restrict__ bucketCur, uint32_t* __restrict__ pairs,
    int Ee, int nbuck)
{
    __shared__ int cntL[MAXB], scanL[MAXB], exclL[MAXB], curL[MAXB], gbaseL[MAXB];
    __shared__ uint32_t sortedV[TILE1];
    __shared__ uint16_t sortedB[TILE1];
    const int t = threadIdx.x;
    const int base = blockIdx.x * TILE1;
    cntL[t] = 0;
    __syncthreads();
    uint32_t vq[8]; int bq[8];
    #pragma unroll
    for (int q = 0; q < 8; ++q) {
        int i = base + q * 512 + t;
        if (i < Ee) {
            int s = srcI[i], d = dstI[i];
            bq[q] = s >> 8;
            vq[q] = ((uint32_t)d << 8) | (uint32_t)(s & 255);
            atomicAdd(&cntL[bq[q]], 1);
        } else bq[q] = -1;
    }
    __syncthreads();
    scanL[t] = cntL[t];
    __syncthreads();
    for (int off = 1; off < MAXB; off <<= 1) {
        int add = (t >= off) ? scanL[t - off] : 0;
        __syncthreads();
        scanL[t] += add;
        __syncthreads();
    }
    int excl = scanL[t] - cntL[t];
    exclL[t] = excl;
    curL[t] = excl;
    if (t < nbuck && cntL[t] > 0)
        gbaseL[t] = atomicAdd(&bucketCur[t], cntL[t]);
    __syncthreads();
    #pragma unroll
    for (int q = 0; q < 8; ++q) {
        if (bq[q] >= 0) {
            int pos = atomicAdd(&curL[bq[q]], 1);
            sortedV[pos] = vq[q];
            sortedB[pos] = (uint16_t)bq[q];
        }
    }
    __syncthreads();
    int tcount = min(TILE1, Ee - base);
    for (int j = t; j < tcount; j += 512) {
        int b = sortedB[j];
        pairs[gbaseL[b] + (j - exclL[b])] = sortedV[j];
    }
}

__global__ __launch_bounds__(256) void pass2_k(
    const uint32_t* __restrict__ pairs, const int* __restrict__ bucketStart,
    int* __restrict__ rowStart, int* __restrict__ colI, int Nn)
{
    __shared__ int ncnt[256], sd[256], lcur[256];
    int b = blockIdx.x, t = threadIdx.x;
    int n0 = b << 8;
    int s = bucketStart[b], e = bucketStart[b + 1];
    ncnt[t] = 0;
    __syncthreads();
    for (int p = s + t; p < e; p += 256)
        atomicAdd(&ncnt[pairs[p] & 255], 1);
    __syncthreads();
    int v = ncnt[t];
    sd[t] = v;
    __syncthreads();
    for (int off = 1; off < 256; off <<= 1) {
        int add = (t >= off) ? sd[t - off] : 0;
        __syncthreads();
        sd[t] += add;
        __syncthreads();
    }
    int start = s + sd[t] - v;
    lcur[t] = start;
    if (n0 + t < Nn) rowStart[n0 + t] = start;
    __syncthreads();
    for (int p = s + t; p < e; p += 256) {
        uint32_t pv = pairs[p];
        int q = atomicAdd(&lcur[pv & 255], 1);
        colI[q] = (int)(pv >> 8);
    }
}

// ---------------------------------------------------------------------------
// f16 MFMA GEMM, R12 rewrite of the K-loop:
//  - global_load_lds width=16 staging (B always; A when AMODE=1): no VGPR
//    roundtrip, no per-thread staging address VALU (guide common-mistake #1,
//    m193: +67% isolated).
//  - linear LDS [rows][32] halves (64B rows, NO padding -- gload_lds needs
//    contiguous dest). ds_read_b128 fragment reads verified conflict-free:
//    16 consecutive rows x 16B span 256 consecutive words = 8 words/bank.
//  - double-buffered 2-phase schedule: stage(buf^1) issued BEFORE ds_read/
//    MFMA of buf, ONE barrier per K-step (T3-minimum recipe).
//  - A-row OOB handled by clamping to M-1 (AMODE=1; those rows' outputs are
//    discarded by the guarded epilogues). AMODE=0 keeps the guarded VGPR
//    convert path for A (fp32/bf16 -> f16 has no gload_lds form).
// Tiling/wave layout/epilogues unchanged from the proven R8/R11 version.
// OMODE 0: collator + fused classifier partials. OMODE 1: fp16 out + scores.
// ---------------------------------------------------------------------------
template <int AMODE, int OMODE>
__global__ __launch_bounds__(256) void gemm_k(
    const void* __restrict__ Ap, const __half* __restrict__ B,
    const float* __restrict__ bias, void* __restrict__ Cp, int M,
    const int* __restrict__ flagp,
    const float* __restrict__ a1w, const float* __restrict__ a1b,
    const float* __restrict__ a2w, const float* __restrict__ a2b,
    float* __restrict__ a1v, __half* __restrict__ a2v)
{
    // 34.8 KB: staging dbuf uses [0,32K); epilogue Cs[128][136] reuses all.
    __shared__ __align__(16) char smem[128 * 136 * 2];
    const int tid  = threadIdx.x;
    const int row0 = blockIdx.x * 128;
    const int col0 = blockIdx.y * 128;
    const int wave = tid >> 6, lane = tid & 63;
    const int m0w = (wave & 1) * 64;
    const int n0w = (wave >> 1) * 64;
    const int lm = lane & 15, lg = lane >> 4;
    const int isbf = (AMODE == 0) ? *flagp : 0;

    const __half* A = (const __half*)Ap;
    // gload lane mapping: lane -> (row base + lane>>2, kc = lane&3); 16B each.
    const int lrow = wave * 32 + (lane >> 2);
    const int kcL  = lane & 3;
    // A source rows clamped (OOB rows discarded at epilogue)
    const size_t arow0 = (size_t)min(row0 + lrow,      M - 1) * CDIM;
    const size_t arow1 = (size_t)min(row0 + lrow + 16, M - 1) * CDIM;
    const size_t brow0 = (size_t)(col0 + lrow) * CDIM;
    const size_t brow1 = (size_t)(col0 + lrow + 16) * CDIM;

    f32x4 acc[4][4] = {};

    auto stageAB = [&](int buf, int k0) {
        char* Ab = smem + buf * 16384;
        char* Bb = Ab + 8192;
        if constexpr (AMODE == 1) {
            __builtin_amdgcn_global_load_lds(GLOBAL_AS(A + arow0 + k0 + kcL * 8),
                LDS_AS(Ab + wave * 2048), 16, 0, 0);
            __builtin_amdgcn_global_load_lds(GLOBAL_AS(A + arow1 + k0 + kcL * 8),
                LDS_AS(Ab + wave * 2048 + 1024), 16, 0, 0);
        } else {
            #pragma unroll
            for (int l = 0; l < 2; ++l) {
                int c = tid + l * 256;
                int m = c >> 2, kc = c & 3;
                int gr = row0 + m;
                uint4 q = make_uint4(0u, 0u, 0u, 0u);
                if (gr < M) {
                    __half hv[8];
                    if (isbf) {
                        const uint4 qb = *(const uint4*)((const __hip_bfloat16*)Ap
                                           + (size_t)gr * CDIM + k0 + kc * 8);
                        const uint32_t* w = (const uint32_t*)&qb;
                        #pragma unroll
                        for (int p = 0; p < 4; ++p) {
                            hv[2*p]   = __float2half(__uint_as_float((w[p] & 0xffffu) << 16));
                            hv[2*p+1] = __float2half(__uint_as_float(w[p] & 0xffff0000u));
                        }
                    } else {
                        const float* Af = (const float*)Ap + (size_t)gr * CDIM + k0 + kc * 8;
                        const float4 f0 = *(const float4*)Af;
                        const float4 f1 = *(const float4*)(Af + 4);
                        hv[0]=__float2half(f0.x); hv[1]=__float2half(f0.y);
                        hv[2]=__float2half(f0.z); hv[3]=__float2half(f0.w);
                        hv[4]=__float2half(f1.x); hv[5]=__float2half(f1.y);
                        hv[6]=__float2half(f1.z); hv[7]=__float2half(f1.w);
                    }
                    q = *(uint4*)hv;
                }
                *(uint4*)(Ab + m * 64 + kc * 16) = q;
            }
        }
        __builtin_amdgcn_global_load_lds(GLOBAL_AS(B + brow0 + k0 + kcL * 8),
            LDS_AS(Bb + wave * 2048), 16, 0, 0);
        __builtin_amdgcn_global_load_lds(GLOBAL_AS(B + brow1 + k0 + kcL * 8),
            LDS_AS(Bb + wave * 2048 + 1024), 16, 0, 0);
    };

    stageAB(0, 0);
    __syncthreads();
    int cur = 0;
    for (int kt = 0; kt < 8; ++kt) {
        if (kt < 7) stageAB(cur ^ 1, (kt + 1) * 32);
        const char* Ab = smem + cur * 16384;
        const char* Bb = Ab + 8192;
        f16x8 af[4], bfr[4];
        #pragma unroll
        for (int i = 0; i < 4; ++i)
            af[i] = *(const f16x8*)(Ab + (m0w + i * 16 + lm) * 64 + lg * 16);
        #pragma unroll
        for (int j = 0; j < 4; ++j)
            bfr[j] = *(const f16x8*)(Bb + (n0w + j * 16 + lm) * 64 + lg * 16);
        #pragma unroll
        for (int i = 0; i < 4; ++i)
            #pragma unroll
            for (int j = 0; j < 4; ++j)
                acc[i][j] = __builtin_amdgcn_mfma_f32_16x16x32_f16(
                    af[i], bfr[j], acc[i][j], 0, 0, 0);
        __syncthreads();
        cur ^= 1;
    }

    if constexpr (OMODE == 1) {
        // fp16 tile -> LDS; n-major coalesced stores + fused scores
        __half (*Cs)[136] = (__half(*)[136])smem;
        #pragma unroll
        for (int i = 0; i < 4; ++i)
            #pragma unroll
            for (int r = 0; r < 4; ++r) {
                int lr = m0w + i * 16 + lg * 4 + r;
                #pragma unroll
                for (int j = 0; j < 4; ++j)
                    Cs[lr][n0w + j * 16 + lm] = __float2half(acc[i][j][r]);
            }
        __syncthreads();
        __half* C = (__half*)Cp;
        #pragma unroll
        for (int l = 0; l < 8; ++l) {
            int c = tid + l * 256;
            int rr = c >> 4, cc = c & 15;
            int gr = row0 + rr;
            if (gr < M)
                *(uint4*)(C + (size_t)gr * CDIM + col0 + cc * 8) = *(uint4*)(&Cs[rr][cc * 8]);
        }
        // fused scores: thread t -> (row t>>1, head-sel t&1); block covers 2 heads
        {
            int row = tid >> 1, hsel = tid & 1;
            int gr = row0 + row;
            if (gr < M) {
                int ghead = (col0 >> 6) + hsel;
                const float* w1 = a1w + ghead * 64;
                const float* w2 = a2w + ghead * 64;
                const uint* cp = (const uint*)&Cs[row][hsel * 64];
                float s1 = 0.f, s2 = 0.f;
                #pragma unroll
                for (int j = 0; j < 32; ++j) {
                    uint u = cp[j];
                    float2 f = __half22float2(*(__half2*)&u);
                    s1 += f.x * w1[2*j] + f.y * w1[2*j+1];
                    s2 += f.x * w2[2*j] + f.y * w2[2*j+1];
                }
                a1v[(size_t)gr * H + ghead] = s1 + a1b[ghead];
                a2v[(size_t)gr * H + ghead] = __float2half(s2 + a2b[ghead]);
            }
        }
    } else {
        // collator + fused classifier partials (R8). feat stays in registers.
        const float* Wc4 = a1w;     // Wcls [OUTC][CDIM] fp32
        float* pcls = a1v;          // [M][4][OUTC] partials
        const int slot = blockIdx.y * 2 + (wave >> 1);
        float wv[OUTC][4];
        #pragma unroll
        for (int o = 0; o < OUTC; ++o)
            #pragma unroll
            for (int j = 0; j < 4; ++j)
                wv[o][j] = Wc4[o * CDIM + col0 + n0w + j * 16 + lm];
        #pragma unroll
        for (int i = 0; i < 4; ++i)
            #pragma unroll
            for (int r = 0; r < 4; ++r) {
                int grow = row0 + m0w + i * 16 + lg * 4 + r;
                if (grow < M) {
                    float po[OUTC] = {0.f, 0.f, 0.f, 0.f};
                    #pragma unroll
                    for (int j = 0; j < 4; ++j) {
                        int gcol = col0 + n0w + j * 16 + lm;
                        float t = fmaxf(acc[i][j][r] + bias[gcol], 0.f);
                        #pragma unroll
                        for (int o = 0; o < OUTC; ++o)
                            po[o] = fmaf(t, wv[o][j], po[o]);
                    }
                    // reduce over the 16 lanes (lm) sharing this row
                    #pragma unroll
                    for (int m = 1; m < 16; m <<= 1)
                        #pragma unroll
                        for (int o = 0; o < OUTC; ++o)
                            po[o] += __shfl_xor(po[o], m);
                    if (lm < OUTC) {
                        float v = (lm == 0) ? po[0] : (lm == 1) ? po[1]
                                : (lm == 2) ? po[2] : po[3];
                        pcls[((size_t)grow * 4 + slot) * OUTC + lm] = v;
                    }
                }
            }
        (void)Cp;
    }
}

// ---------------------------------------------------------------------------
// Edge aggregation (R11, frozen): fused escore, branchless batch, fp16 a2.
// At the ~3.8 TB/s random-512B-gather service ceiling (R6 post-mortem):
// 418 MB / 3.8 TB/s = ~126us = measured. Do not touch without a traffic
// reduction idea.
// ---------------------------------------------------------------------------
__global__ __launch_bounds__(256) void agg_k(
    const __half* __restrict__ h,
    const float* __restrict__ a1v, const __half* __restrict__ a2v,
    const int* __restrict__ rowStart, const int* __restrict__ colI,
    const float* __restrict__ bias, __half* __restrict__ outp, int relu, int Nn)
{
    int tid = threadIdx.x;
    int wave = tid >> 6, lane = tid & 63;
    int n = blockIdx.x * 4 + wave;
    if (n >= Nn) return;
    int head = lane >> 4;
    int s = rowStart[n], e = rowStart[n + 1];
    float ac0 = 0.f, ac1 = 0.f, ac2 = 0.f, ac3 = 0.f, den = 0.f;
    const __half* hl = h + lane * 4;
    const float a1n = a1v[(size_t)n * H + head];

    for (int p0 = s; p0 < e; p0 += 8) {
        const int cnt = e - p0;            // wave-uniform; >= 1
        int d[8]; float a2q[8]; ushort4 u[8];
        #pragma unroll
        for (int q = 0; q < 8; ++q) {
            int p = p0 + ((q < cnt) ? q : 0);   // clamped: always < e
            d[q] = colI[p];
        }
        #pragma unroll
        for (int q = 0; q < 8; ++q) {
            u[q] = *(const ushort4*)(hl + (size_t)d[q] * CDIM);
            a2q[q] = __half2float(a2v[(size_t)d[q] * H + head]);
        }
        #pragma unroll
        for (int q = 0; q < 8; ++q) {
            float z = a1n + a2q[q];
            z = (z > 0.f) ? z : ALPHA * z;
            float svq = (q < cnt) ? __expf(z) : 0.f;
            den += svq;
            ac0 = fmaf(svq, __half2float(__ushort_as_half(u[q].x)), ac0);
            ac1 = fmaf(svq, __half2float(__ushort_as_half(u[q].y)), ac1);
            ac2 = fmaf(svq, __half2float(__ushort_as_half(u[q].z)), ac2);
            ac3 = fmaf(svq, __half2float(__ushort_as_half(u[q].w)), ac3);
        }
    }

    den = (den > 0.f) ? den : 1.f;
    const float4 b4 = *(const float4*)(bias + lane * 4);
    float r0 = ac0 / den + b4.x;
    float r1 = ac1 / den + b4.y;
    float r2 = ac2 / den + b4.z;
    float r3 = ac3 / den + b4.w;
    if (relu) {
        r0 = fmaxf(r0, 0.f); r1 = fmaxf(r1, 0.f);
        r2 = fmaxf(r2, 0.f); r3 = fmaxf(r3, 0.f);
    }
    ushort4 o;
    o.x = __half_as_ushort(__float2half(r0));
    o.y = __half_as_ushort(__float2half(r1));
    o.z = __half_as_ushort(__float2half(r2));
    o.w = __half_as_ushort(__float2half(r3));
    *(ushort4*)(outp + (size_t)n * CDIM + lane * 4) = o;
}

// ---------------------------------------------------------------------------
// Classifier finalize (R8): sum the 4 per-wave partials + bias; dtype per flag.
// ---------------------------------------------------------------------------
__global__ void cls2_k(const float* __restrict__ pcls, const float* __restrict__ bcls,
                       void* __restrict__ out, int Nn, const int* __restrict__ flagp)
{
    int n = blockIdx.x * 256 + threadIdx.x;
    if (n >= Nn) return;
    const float4 p0 = *(const float4*)(pcls + (size_t)n * 16);
    const float4 p1 = *(const float4*)(pcls + (size_t)n * 16 + 4);
    const float4 p2 = *(const float4*)(pcls + (size_t)n * 16 + 8);
    const float4 p3 = *(const float4*)(pcls + (size_t)n * 16 + 12);
    float r0 = p0.x + p1.x + p2.x + p3.x + bcls[0];
    float r1 = p0.y + p1.y + p2.y + p3.y + bcls[1];
    float r2 = p0.z + p1.z + p2.z + p3.z + bcls[2];
    float r3 = p0.w + p1.w + p2.w + p3.w + bcls[3];
    if (*flagp) {
        __hip_bfloat16* o = (__hip_bfloat16*)out + (size_t)n * OUTC;
        o[0] = __float2bfloat16(r0); o[1] = __float2bfloat16(r1);
        o[2] = __float2bfloat16(r2); o[3] = __float2bfloat16(r3);
    } else {
        float* o = (float*)out + (size_t)n * OUTC;
        o[0] = r0; o[1] = r1; o[2] = r2; o[3] = r3;
    }
}

// ---------------------------------------------------------------------------
extern "C" void kernel_launch(void* const* d_in, const int* in_sizes, int n_in,
                              void* d_out, int out_size, void* d_ws, size_t ws_size,
                              hipStream_t stream)
{
    const void* x  = d_in[0];
    const int*  ei = (const int*)d_in[1];

    const int Nn = in_sizes[0] / CDIM;   // 100000
    const int Ee = in_sizes[1] / 2;      // 1600000
    const int* srcI = ei;
    const int* dstI = ei + Ee;

    char* wsp = (char*)d_ws;
    size_t off = 0;
    auto alloc = [&](size_t bytes) -> void* {
        void* p = wsp + off;
        off += (bytes + 255) & ~(size_t)255;
        return p;
    };
    __half* hA   = (__half*)alloc((size_t)Nn * CDIM * 2);  // 51.2 MB
    __half* hB   = (__half*)alloc((size_t)Nn * CDIM * 2);  // 51.2 MB
    float*  a1v       = (float*)alloc((size_t)Nn * H * 4);
    __half* a2h       = (__half*)alloc((size_t)Nn * H * 2); // 0.8 MB fp16
    float*  pcls      = (float*)alloc((size_t)Nn * 4 * OUTC * 4); // 6.4 MB
    int*    rowStart  = (int*)alloc((size_t)(Nn + 1) * 4);
    int*    colI      = (int*)alloc((size_t)Ee * 4);       // 6.4 MB
    uint32_t* pairs   = (uint32_t*)alloc((size_t)Ee * 4);  // 6.4 MB packed
    int*    bucketCnt   = (int*)alloc(MAXB * 4);
    int*    bucketCur   = (int*)alloc(MAXB * 4);
    int*    bucketStart = (int*)alloc((MAXB + 1) * 4);
    int*    flag      = (int*)alloc(256);
    float*  wconv     = (float*)alloc((size_t)200000 * 4);
    __half* wh        = (__half*)alloc((size_t)200000 * 2);
    (void)ws_size; (void)n_in; (void)out_size;

    // dtype detect + weight conversion (proven machinery)
    detect_k<<<1, 256, 0, stream>>>((const uint32_t*)x, flag);
    WPtrs wp;
    int woff = 0;
    for (int i = 0; i < NW; ++i) {
        wp.p[i] = d_in[2 + i];
        wp.sz[i] = in_sizes[2 + i];
        wp.off[i] = woff;
        woff += in_sizes[2 + i];
    }
    {
        dim3 cgrid(256, NW);
        convert_k<<<cgrid, 256, 0, stream>>>(wp, wconv, wh, flag);
    }
    const float*  a11wf = wconv + wp.off[1];
    const float*  a11bf = wconv + wp.off[2];
    const float*  a12wf = wconv + wp.off[3];
    const float*  a12bf = wconv + wp.off[4];
    const float*  b1f   = wconv + wp.off[5];
    const float*  a21wf = wconv + wp.off[7];
    const float*  a21bf = wconv + wp.off[8];
    const float*  a22wf = wconv + wp.off[9];
    const float*  a22bf = wconv + wp.off[10];
    const float*  b2f   = wconv + wp.off[11];
    const float*  bcf   = wconv + wp.off[13];
    const float*  Wclsf = wconv + wp.off[14];
    const float*  bclsf = wconv + wp.off[15];
    const __half* W1h   = wh + wp.off[0];
    const __half* W2h   = wh + wp.off[6];
    const __half* Wch   = wh + wp.off[12];

    const int NB = (Nn + 255) / 256;          // node blocks (391)
    const int NBUCK = (Nn + 255) >> 8;        // buckets (391, <= MAXB)
    const int TB = (Ee + TILE1 - 1) / TILE1;  // edge tiles (391)

    // CSR build (R9 binning pipeline)
    hipMemsetAsync(bucketCnt, 0, MAXB * 4, stream);
    bhist_k<<<TB, 512, 0, stream>>>(srcI, bucketCnt, Ee, NBUCK);
    bscan_k<<<1, 512, 0, stream>>>(bucketCnt, bucketCur, bucketStart, rowStart,
                                   NBUCK, Nn, Ee);
    pass1_k<<<TB, 512, 0, stream>>>(srcI, dstI, bucketCur, pairs, Ee, NBUCK);
    pass2_k<<<NBUCK, 256, 0, stream>>>(pairs, bucketStart, rowStart, colI, Nn);

    dim3 ggrid((Nn + 127) / 128, CDIM / 128);   // (782, 2)
    const int AB = (Nn + 3) / 4;                // 4 nodes (waves) per block

    // Layer 1: gemm(raw x) -> hA (+ fused scores); agg (fused escore) -> hB
    gemm_k<0, 1><<<ggrid, 256, 0, stream>>>(x, W1h, nullptr, hA, Nn, flag,
                                            a11wf, a11bf, a12wf, a12bf, a1v, a2h);
    agg_k<<<AB, 256, 0, stream>>>(hA, a1v, a2h, rowStart, colI, b1f, hB, 1, Nn);

    // Layer 2: gemm(hB) -> hA (+ fused scores); agg (fused escore) -> hB
    gemm_k<1, 1><<<ggrid, 256, 0, stream>>>(hB, W2h, nullptr, hA, Nn, flag,
                                            a21wf, a21bf, a22wf, a22bf, a1v, a2h);
    agg_k<<<AB, 256, 0, stream>>>(hA, a1v, a2h, rowStart, colI, b2f, hB, 0, Nn);

    // Collator + fused classifier partials; then finalize
    gemm_k<1, 0><<<ggrid, 256, 0, stream>>>(hB, Wch, bcf, nullptr, Nn, flag,
                                            Wclsf, nullptr, nullptr, nullptr,
                                            pcls, nullptr);
    cls2_k<<<NB, 256, 0, stream>>>(pcls, bclsf, d_out, Nn, flag);
}